// Round 12
// baseline (281.868 us; speedup 1.0000x reference)
//
#include <hip/hip_runtime.h>

// ---------------------------------------------------------------------------
// MRLR feature extractor, round 12: single fused middle kernel.
//   S1=M^2*2^-27, S2=S1^2 (M^14 = S2^3 S1):
//   Y=S1 C1; P=S2 Y; P2=S2 P; Q=S2 P2; W1=proj(Q)
//   TMP=M-W1 M; M2=TMP-TMP W1; C2'=C2-W1 C2; same chain -> W2; T=W1+W2
//   out = T X.
// k1: item-pinned split-K partials (r8/r11-proven).
// kcoop: ONE kernel, 104 WGs (13/item, item=wg&7 -> XCD-pinned), 13 phases
//        separated by a device-scope generation barrier (co-residency
//        guaranteed: 104 WGs <= 256 CUs).
// k4: out = T X.
// ---------------------------------------------------------------------------

#define TID ((int)threadIdx.x)
typedef float4 f4;

#define SC27 (1.0f/134217728.0f)   // 2^-27
#define NWG  104

__device__ __forceinline__ f4 ld4(const float* p) { return *(const f4*)p; }
__device__ __forceinline__ void st4(float* p, f4 v) { *(f4*)p = v; }
__device__ __forceinline__ f4 f4zero() { return make_float4(0.f,0.f,0.f,0.f); }
__device__ __forceinline__ f4 add4(f4 a, f4 b){ return make_float4(a.x+b.x,a.y+b.y,a.z+b.z,a.w+b.w); }
__device__ __forceinline__ f4 sub4(f4 a, f4 b){ return make_float4(a.x-b.x,a.y-b.y,a.z-b.z,a.w-b.w); }
__device__ __forceinline__ f4 scl4(f4 a, float s){ return make_float4(a.x*s,a.y*s,a.z*s,a.w*s); }
__device__ __forceinline__ void fma4(f4& a, float s, f4 v) {
  a.x = fmaf(s,v.x,a.x); a.y = fmaf(s,v.y,a.y); a.z = fmaf(s,v.z,a.z); a.w = fmaf(s,v.w,a.w);
}
__device__ __forceinline__ float dot4(f4 a, f4 b, float acc) {
  acc = fmaf(a.x,b.x,acc); acc = fmaf(a.y,b.y,acc);
  acc = fmaf(a.z,b.z,acc); acc = fmaf(a.w,b.w,acc); return acc;
}
__device__ __forceinline__ void trimap(int t, int& ti, int& tj) {
  int rem = t; ti = 0;
  #pragma unroll
  for (int r = 0; r < 12; ++r) { int w = 12 - r; if (rem < w) { ti = r; break; } rem -= w; }
  tj = ti + rem;
}
__device__ __forceinline__ void init8(f4 acc[8][2]) {
  #pragma unroll
  for (int a = 0; a < 8; ++a) { acc[a][0] = f4zero(); acc[a][1] = f4zero(); }
}
__device__ __forceinline__ void tile8_step(f4 acc[8][2], const float* u, const float* v) {
  f4 u0 = ld4(u), u1 = ld4(u+4), v0 = ld4(v), v1 = ld4(v+4);
  float aa[8] = {u0.x,u0.y,u0.z,u0.w,u1.x,u1.y,u1.z,u1.w};
  #pragma unroll
  for (int a = 0; a < 8; ++a) { fma4(acc[a][0], aa[a], v0); fma4(acc[a][1], aa[a], v1); }
}

// ---------------------------------------------------------------------------
// Device-scope generation barrier.  bar[0]=arrive count, bar[1]=generation.
// Safe: all NWG blocks co-resident (104 <= 256 CUs).  __threadfence() at
// agent scope emits the L2 writeback/invalidate needed across XCDs.
// ---------------------------------------------------------------------------
__device__ __forceinline__ void gridbar(unsigned* bar, unsigned nwg) {
  __syncthreads();
  if (threadIdx.x == 0) {
    __threadfence();
    unsigned g = __hip_atomic_load(bar + 1, __ATOMIC_RELAXED, __HIP_MEMORY_SCOPE_AGENT);
    unsigned a = __hip_atomic_fetch_add(bar, 1u, __ATOMIC_ACQ_REL, __HIP_MEMORY_SCOPE_AGENT);
    if (a == nwg - 1u) {
      __hip_atomic_store(bar, 0u, __ATOMIC_RELAXED, __HIP_MEMORY_SCOPE_AGENT);
      __hip_atomic_store(bar + 1, g + 1u, __ATOMIC_RELEASE, __HIP_MEMORY_SCOPE_AGENT);
    } else {
      while (__hip_atomic_load(bar + 1, __ATOMIC_ACQUIRE, __HIP_MEMORY_SCOPE_AGENT) == g)
        __builtin_amdgcn_s_sleep(8);
    }
    __threadfence();
  }
  __syncthreads();
}

// ---------------------------------------------------------------------------
// k1 (r8/r11-proven): grid nch*8 (item = bid&7), block 512.
// ---------------------------------------------------------------------------
__global__ __launch_bounds__(512) void k1_partials(
    const float* __restrict__ x, const float* __restrict__ b01,
    const float* __restrict__ b02, float* __restrict__ part,
    int nch, int nsc) {
  __shared__ __align__(16) float Xst[48][100];
  __shared__ __align__(16) float Bs[48][52];
  __shared__ __align__(16) float red[9600];
  int bid = blockIdx.x;
  int item = bid & 7, kc = bid >> 3;
  const float* X = x + (size_t)item * 96 * 9216;
  float* base = part + (size_t)(item * nch + kc) * 9600;

  int t = TID, kh = 0, tt = 0;
  const float* ap = nullptr; const float* bp = nullptr;
  float* op = nullptr; int os = 0; bool isM = false;
  bool active = (t < 450);
  if (active) {
    kh = t / 150; tt = t % 150;
    if (tt < 78) {
      int ti, tj; trimap(tt, ti, tj);
      ap = &Xst[0][ti*8]; bp = &Xst[0][tj*8];
      op = base + tt*64; os = 8; isM = true;
    } else {
      int u = tt - 78; int i0 = (u/6)*8, c0 = (u%6)*8;
      ap = &Xst[0][i0]; bp = &Bs[0][c0];
      op = base + 4992 + i0*48 + c0; os = 48;
    }
  }

  f4 acc[8][2]; init8(acc);

  for (int sc = 0; sc < nsc; ++sc) {
    int k0 = (kc * nsc + sc) * 48;
    __syncthreads();
    for (int e = TID; e < 1152; e += 512) {
      int i = e / 12, kq = (e % 12) * 4;
      f4 v = ld4(&X[(size_t)i * 9216 + k0 + kq]);
      Xst[kq][i] = v.x; Xst[kq+1][i] = v.y; Xst[kq+2][i] = v.z; Xst[kq+3][i] = v.w;
    }
    for (int e = TID; e < 384; e += 512) {
      int kk = e / 8, cq = (e % 8) * 4;
      st4(&Bs[kk][cq], ld4(&b01[(size_t)(k0 + kk) * 32 + cq]));
    }
    for (int e = TID; e < 192; e += 512) {
      int kk = e / 4, cq = (e % 4) * 4;
      st4(&Bs[kk][32+cq], ld4(&b02[(size_t)(k0 + kk) * 16 + cq]));
    }
    __syncthreads();
    if (active) {
      int asr = 100, bsr = isM ? 100 : 52;
      const float* ar = ap + kh * asr;
      const float* br = bp + kh * bsr;
      #pragma unroll 4
      for (int kk = kh; kk < 48; kk += 3) {
        tile8_step(acc, ar, br);
        ar += 3 * asr; br += 3 * bsr;
      }
    }
  }
  __syncthreads();
  if (active && kh == 1) {
    #pragma unroll
    for (int a = 0; a < 8; ++a) { st4(&red[tt*64+a*8], acc[a][0]); st4(&red[tt*64+a*8+4], acc[a][1]); }
  }
  __syncthreads();
  if (active && kh == 0) {
    #pragma unroll
    for (int a = 0; a < 8; ++a) {
      acc[a][0] = add4(acc[a][0], ld4(&red[tt*64+a*8]));
      acc[a][1] = add4(acc[a][1], ld4(&red[tt*64+a*8+4]));
    }
  }
  __syncthreads();
  if (active && kh == 2) {
    #pragma unroll
    for (int a = 0; a < 8; ++a) { st4(&red[tt*64+a*8], acc[a][0]); st4(&red[tt*64+a*8+4], acc[a][1]); }
  }
  __syncthreads();
  if (active && kh == 0) {
    #pragma unroll
    for (int a = 0; a < 8; ++a) {
      f4 s0 = add4(acc[a][0], ld4(&red[tt*64+a*8]));
      f4 s1 = add4(acc[a][1], ld4(&red[tt*64+a*8+4]));
      st4(op + a*os, s0); st4(op + a*os + 4, s1);
    }
  }
}

// ---------------------------------------------------------------------------
// Wave-register Gauss-Jordan (stride-68 aug), verified math r7-r11.
// ---------------------------------------------------------------------------
template<int R>
__device__ void gj_wave(float* aug, int lane) {
  float col[R];
  if (lane < R) {
    #pragma unroll
    for (int i = 0; i < R; ++i) col[i] = aug[i*68 + lane];
  } else {
    #pragma unroll
    for (int i = 0; i < R; ++i) col[i] = (i == lane - R) ? 1.f : 0.f;
  }
  #pragma unroll
  for (int c = 0; c < R; ++c) {
    float pc = __shfl(col[c], c);
    float rp = 1.f / pc;
    bool isc = (lane == c);
    #pragma unroll
    for (int i = 0; i < R; ++i) {
      if (i == c) continue;
      float fi = __shfl(col[i], c) * rp;
      float v = fmaf(-fi, col[c], col[i]);
      col[i] = isc ? 0.f : v;
    }
  }
  #pragma unroll
  for (int i = 0; i < R; ++i) {
    float d = __shfl(col[i], i);
    col[i] = col[i] / d;
  }
  if (lane >= R) {
    #pragma unroll
    for (int i = 0; i < R; ++i) aug[i*68 + lane] = col[i];
  }
}

// ---------------------------------------------------------------------------
// kcoop helpers (smem layout: Bs[96][100]@0, As[8][100]@9600, Ts[96][36]@10400;
// proj overlay: Ps[96][36]@9600, Qs[96][36]@13056, aug[32][68]@16512,
// QKs[8][32]@18688; total 18944 floats = 75.8 KB)
// ---------------------------------------------------------------------------
__device__ __forceinline__ void stage_full(float* Bs, const float* src, int t) {
  for (int e = t; e < 2304; e += 256) {
    int r = e / 24, cq = (e % 24) * 4;
    st4(&Bs[r*100 + cq], ld4(&src[r*96 + cq]));
  }
}
__device__ __forceinline__ void stage_slab(float* As, const float* src, int row0, int t) {
  if (t < 192) {
    int r = t / 24, cq = (t % 24) * 4;
    st4(&As[r*100 + cq], ld4(&src[(size_t)(row0 + r)*96 + cq]));
  }
}
__device__ __forceinline__ void stage_thin(float* Ts, const float* src, int istr, int nq, int t) {
  for (int e = t; e < 96*nq; e += 256) {
    int r = e / nq, cq = (e % nq) * 4;
    st4(&Ts[r*36 + cq], ld4(&src[(size_t)r*istr + cq]));
  }
}
__device__ __forceinline__ void square_slab(const float* As, const float* Bs,
    const float* Sub, float* D, float scale, int w, int t) {
  if (t < 192) {
    int rl = t / 24, jb = (t % 24) * 4;
    f4 acc = f4zero();
    #pragma unroll 8
    for (int k = 0; k < 96; ++k) fma4(acc, As[rl*100 + k], ld4(&Bs[k*100 + jb]));
    int r = w*8 + rl;
    if (Sub) acc = sub4(ld4(&Sub[r*96 + jb]), acc);
    else     acc = scl4(acc, scale);
    st4(&D[r*96 + jb], acc);
  }
}
__device__ __forceinline__ void thin_full(const float* A100, const float* Ts,
    float* To, int tos, int TW, int tsub, int t) {
  int nact = (TW == 32) ? 192 : 96;
  if (t < nact) {
    int r  = (TW == 32) ? (t >> 1) : t;
    int c0 = (TW == 32) ? (t & 1) * 16 : 0;
    f4 acc[4] = {f4zero(), f4zero(), f4zero(), f4zero()};
    #pragma unroll 4
    for (int k = 0; k < 96; ++k) {
      float a = A100[r*100 + k];
      const float* tr = &Ts[k*36 + c0];
      fma4(acc[0], a, ld4(tr));   fma4(acc[1], a, ld4(tr+4));
      fma4(acc[2], a, ld4(tr+8)); fma4(acc[3], a, ld4(tr+12));
    }
    if (tsub) {
      #pragma unroll
      for (int u = 0; u < 4; ++u) acc[u] = sub4(ld4(&Ts[r*36 + c0 + u*4]), acc[u]);
    }
    #pragma unroll
    for (int u = 0; u < 4; ++u) st4(&To[(size_t)r*tos + c0 + u*4], acc[u]);
  }
}
__device__ __forceinline__ void thin_slab(const float* As, const float* Ts,
    float* To, int w, int TW, int t) {
  int nq = TW >> 2;
  if (t < 8*nq) {
    int rl = t / nq, c4 = (t % nq) * 4;
    f4 acc = f4zero();
    #pragma unroll 8
    for (int k = 0; k < 96; ++k) fma4(acc, As[rl*100 + k], ld4(&Ts[k*36 + c4]));
    st4(&To[(size_t)(w*8 + rl)*32 + c4], acc);
  }
}

template<int TW>
__device__ void proj_phase(const float* Bs /*S-full staged*/, float* Ps, float* Qs,
    float* aug, float* QKs, const float* Pg, float* Wdst, const float* Wadd,
    int w, int t) {
  const int nq = TW >> 2;
  stage_thin(Ps, Pg, 32, nq, t);
  __syncthreads();
  for (int e = t; e < 96*nq; e += 256) {             // Q = S * P
    int r = e / nq, c4 = (e % nq) * 4;
    f4 acc = f4zero();
    #pragma unroll 4
    for (int k = 0; k < 96; ++k) fma4(acc, Bs[r*100 + k], ld4(&Ps[k*36 + c4]));
    st4(&Qs[r*36 + c4], acc);
  }
  __syncthreads();
  for (int e = t; e < TW*nq; e += 256) {             // Gram
    int ar = e / nq, b4 = (e % nq) * 4;
    f4 acc = f4zero();
    #pragma unroll 4
    for (int k = 0; k < 96; ++k) fma4(acc, Qs[k*36 + ar], ld4(&Qs[k*36 + b4]));
    st4(&aug[ar*68 + b4], acc);
  }
  __syncthreads();
  if (t < 2*TW) gj_wave<TW>(aug, t);
  __syncthreads();
  for (int e = t; e < TW*TW; e += 256) {             // K^T -> aug[:,0:TW]
    int m = e / TW, c = e % TW;
    aug[c*68 + m] = aug[m*68 + TW + c];
  }
  __syncthreads();
  for (int e = t; e < 8*TW; e += 256) {              // QK slab
    int rr = e / TW, c = e % TW;
    float acc = 0.f;
    #pragma unroll
    for (int m4 = 0; m4 < TW; m4 += 4)
      acc = dot4(ld4(&Qs[(w*8 + rr)*36 + m4]), ld4(&aug[c*68 + m4]), acc);
    QKs[rr*32 + c] = acc;
  }
  __syncthreads();
  if (t < 192) {                                     // W slab = QK * Q^T
    int rr = t / 24, jb = (t % 24) * 4;
    int r = w*8 + rr;
    f4 acc = f4zero();
    #pragma unroll
    for (int c4 = 0; c4 < TW; c4 += 4) {
      f4 qk = ld4(&QKs[rr*32 + c4]);
      acc.x = dot4(qk, ld4(&Qs[(jb+0)*36 + c4]), acc.x);
      acc.y = dot4(qk, ld4(&Qs[(jb+1)*36 + c4]), acc.y);
      acc.z = dot4(qk, ld4(&Qs[(jb+2)*36 + c4]), acc.z);
      acc.w = dot4(qk, ld4(&Qs[(jb+3)*36 + c4]), acc.w);
    }
    if (Wadd) acc = add4(acc, ld4(&Wadd[r*96 + jb]));
    st4(&Wdst[r*96 + jb], acc);
  }
}

// ---------------------------------------------------------------------------
// kcoop: grid 104 (item = wg&7, w = wg>>3 in [0,13)), block 256.
// ---------------------------------------------------------------------------
__global__ __launch_bounds__(256) void kcoop(
    float* __restrict__ part, float* __restrict__ Mb, float* __restrict__ Cb,
    float* __restrict__ Sb, float* __restrict__ S2b, float* __restrict__ W1b,
    float* __restrict__ Tgb, float* __restrict__ Yb, float* __restrict__ Pb,
    float* __restrict__ CPb, unsigned* __restrict__ bar, int nch) {
  __shared__ __align__(16) float smem[18944];
  float* Bs  = smem;            // [96][100]
  float* As  = smem + 9600;     // [8][100]
  float* Ts  = smem + 10400;    // [96][36]
  float* Ps  = smem + 9600;     // [96][36] (proj overlay)
  float* Qs  = smem + 13056;    // [96][36]
  float* aug = smem + 16512;    // [32][68]
  float* QKs = smem + 18688;    // [8][32]

  int wg = blockIdx.x, t = TID;
  int item = wg & 7, w = wg >> 3;
  float* Mi  = Mb  + (size_t)item * 9216;
  float* Ci  = Cb  + (size_t)item * 4608;
  float* S1i = Sb  + (size_t)item * 9216;   // S1 / TMP / S1'
  float* S2i = S2b + (size_t)item * 9216;
  float* W1i = W1b + (size_t)item * 9216;
  float* Tgi = Tgb + (size_t)item * 9216;
  float* Yi  = Yb  + (size_t)item * 3072;
  float* Pi  = Pb  + (size_t)item * 3072;
  float* CPi = CPb + (size_t)item * 1536;

  // ---- A: reduce partials -> M (mirrored) + C ----
  {
    int q4 = w * 185 + t;
    if (t < 185 && q4 < 2400) {
      int off = q4 * 4;
      const float* p = part + (size_t)item * nch * 9600 + off;
      f4 s = f4zero();
      #pragma unroll 8
      for (int c = 0; c < nch; ++c) s = add4(s, ld4(p + (size_t)c * 9600));
      if (off < 4992) {
        int tile = off >> 6, ww = (off & 63) >> 2;
        int r = ww >> 1, cq = (ww & 1) * 4;
        int ti, tj; trimap(tile, ti, tj);
        int i = ti*8 + r, j = tj*8 + cq;
        st4(&Mi[i*96 + j], s);
        Mi[(j+0)*96 + i] = s.x; Mi[(j+1)*96 + i] = s.y;
        Mi[(j+2)*96 + i] = s.z; Mi[(j+3)*96 + i] = s.w;
      } else {
        st4(&Ci[off - 4992], s);
      }
    }
  }
  gridbar(bar, NWG);

  // ---- B: S1 = M^2 * 2^-27 ----
  if (w < 12) {
    stage_full(Bs, Mi, t); stage_slab(As, Mi, w*8, t);
    __syncthreads();
    square_slab(As, Bs, nullptr, S1i, SC27, w, t);
  }
  gridbar(bar, NWG);

  // ---- C: S2 = S1^2  ||  Y = S1*C1 ----
  if (w < 12) {
    stage_full(Bs, S1i, t); stage_slab(As, S1i, w*8, t);
    __syncthreads();
    square_slab(As, Bs, nullptr, S2i, 1.f, w, t);
  } else {
    stage_full(Bs, S1i, t); stage_thin(Ts, Ci, 48, 8, t);
    __syncthreads();
    thin_full(Bs, Ts, Yi, 32, 32, 0, t);
  }
  gridbar(bar, NWG);

  // ---- D: P = S2*Y ----
  if (w < 12) {
    stage_slab(As, S2i, w*8, t); stage_thin(Ts, Yi, 32, 8, t);
    __syncthreads();
    thin_slab(As, Ts, Pi, w, 32, t);
  }
  gridbar(bar, NWG);

  // ---- E: P2 = S2*P -> Yb ----
  if (w < 12) {
    stage_slab(As, S2i, w*8, t); stage_thin(Ts, Pi, 32, 8, t);
    __syncthreads();
    thin_slab(As, Ts, Yi, w, 32, t);
  }
  gridbar(bar, NWG);

  // ---- F: W1 = proj(S2*P2) ----
  if (w < 12) {
    stage_full(Bs, S2i, t);
    proj_phase<32>(Bs, Ps, Qs, aug, QKs, Yi, W1i, nullptr, w, t);
  }
  gridbar(bar, NWG);

  // ---- G: TMP = M - W1*M -> S1i  ||  C2' = C2 - W1*C2 ----
  if (w < 12) {
    stage_full(Bs, Mi, t); stage_slab(As, W1i, w*8, t);
    __syncthreads();
    square_slab(As, Bs, Mi, S1i, 1.f, w, t);
  } else {
    stage_full(Bs, W1i, t); stage_thin(Ts, Ci + 32, 48, 4, t);
    __syncthreads();
    thin_full(Bs, Ts, CPi, 16, 16, 1, t);
  }
  gridbar(bar, NWG);

  // ---- H: M2 = TMP - TMP*W1 -> Mb ----
  if (w < 12) {
    stage_full(Bs, W1i, t); stage_slab(As, S1i, w*8, t);
    __syncthreads();
    square_slab(As, Bs, S1i, Mi, 1.f, w, t);
  }
  gridbar(bar, NWG);

  // ---- I: S1' = M2^2 * 2^-27 ----
  if (w < 12) {
    stage_full(Bs, Mi, t); stage_slab(As, Mi, w*8, t);
    __syncthreads();
    square_slab(As, Bs, nullptr, S1i, SC27, w, t);
  }
  gridbar(bar, NWG);

  // ---- J: S2' = S1'^2  ||  Y = S1'*C2' ----
  if (w < 12) {
    stage_full(Bs, S1i, t); stage_slab(As, S1i, w*8, t);
    __syncthreads();
    square_slab(As, Bs, nullptr, S2i, 1.f, w, t);
  } else {
    stage_full(Bs, S1i, t); stage_thin(Ts, CPi, 16, 4, t);
    __syncthreads();
    thin_full(Bs, Ts, Yi, 32, 16, 0, t);
  }
  gridbar(bar, NWG);

  // ---- K: P = S2'*Y ----
  if (w < 12) {
    stage_slab(As, S2i, w*8, t); stage_thin(Ts, Yi, 32, 4, t);
    __syncthreads();
    thin_slab(As, Ts, Pi, w, 16, t);
  }
  gridbar(bar, NWG);

  // ---- L: P2 = S2'*P -> Yb ----
  if (w < 12) {
    stage_slab(As, S2i, w*8, t); stage_thin(Ts, Pi, 32, 4, t);
    __syncthreads();
    thin_slab(As, Ts, Yi, w, 16, t);
  }
  gridbar(bar, NWG);

  // ---- M: Tg = W1 + proj(S2'*P2) ----
  if (w < 12) {
    stage_full(Bs, S2i, t);
    proj_phase<16>(Bs, Ps, Qs, aug, QKs, Yi, Tgi, W1i, w, t);
  }
}

// ---------------------------------------------------------------------------
// k4: out = T @ X.  grid 576 (item = bid&7), block 256.
// ---------------------------------------------------------------------------
__global__ __launch_bounds__(256) void k4_out(
    const float* __restrict__ x, const float* __restrict__ Tgg,
    float* __restrict__ out) {
  __shared__ __align__(16) float Tt[96][100];
  int bid = blockIdx.x;
  int item = bid & 7, jb = bid >> 3;
  const float* Tg = Tgg + (size_t)item * 9216;
  for (int e = TID * 4; e < 9216; e += 1024) {
    f4 v = ld4(&Tg[e]);
    int i = e / 96, k = e % 96;
    Tt[k][i] = v.x; Tt[k+1][i] = v.y; Tt[k+2][i] = v.z; Tt[k+3][i] = v.w;
  }
  __syncthreads();

  int jq = (TID % 32) * 4, ig = TID / 32;
  int i0 = ig * 12;
  int col = jb * 128 + jq;
  const float* X = x + (size_t)item * 96 * 9216;
  f4 acc[12];
  #pragma unroll
  for (int a = 0; a < 12; ++a) acc[a] = f4zero();

  for (int k = 0; k < 96; ++k) {
    f4 xv = ld4(&X[(size_t)k * 9216 + col]);
    f4 t0 = ld4(&Tt[k][i0]), t1 = ld4(&Tt[k][i0+4]), t2 = ld4(&Tt[k][i0+8]);
    fma4(acc[0], t0.x, xv); fma4(acc[1], t0.y, xv); fma4(acc[2], t0.z, xv); fma4(acc[3], t0.w, xv);
    fma4(acc[4], t1.x, xv); fma4(acc[5], t1.y, xv); fma4(acc[6], t1.z, xv); fma4(acc[7], t1.w, xv);
    fma4(acc[8], t2.x, xv); fma4(acc[9], t2.y, xv); fma4(acc[10], t2.z, xv); fma4(acc[11], t2.w, xv);
  }
  float* O = out + (size_t)item * 96 * 9216;
  #pragma unroll
  for (int a = 0; a < 12; ++a) st4(&O[(size_t)(i0 + a) * 9216 + col], acc[a]);
}

// ---------------------------------------------------------------------------
extern "C" void kernel_launch(void* const* d_in, const int* in_sizes, int n_in,
                              void* d_out, int out_size, void* d_ws, size_t ws_size,
                              hipStream_t stream) {
  (void)in_sizes; (void)n_in; (void)out_size;
  const float* x   = (const float*)d_in[0];
  const float* b01 = (const float*)d_in[2];
  const float* b02 = (const float*)d_in[4];
  float* out = (float*)d_out;
  float* ws  = (float*)d_ws;

  // buffers after partials: M, C, S1, S2, W1, Tg (96x96 each), Y, P, CP, bar
  const size_t EXTRA = 73728ull*5 + 36864 + 24576*2 + 12288 + 16;
  int nch = (ws_size >= ((size_t)64*8*9600 + EXTRA) * sizeof(float)) ? 64 : 32;
  int nsc = 9216 / nch / 48;

  float* Mb  = ws + (size_t)nch * 8 * 9600;
  float* Cb  = Mb  + 73728;
  float* Sb  = Cb  + 36864;
  float* S2b = Sb  + 73728;
  float* W1b = S2b + 73728;
  float* Tgb = W1b + 73728;
  float* Yb  = Tgb + 73728;
  float* Pb  = Yb  + 24576;
  float* CPb = Pb  + 24576;
  unsigned* bar = (unsigned*)(CPb + 12288);

  hipMemsetAsync((void*)bar, 0, 16, stream);
  k1_partials<<<dim3(nch*8), 512, 0, stream>>>(x, b01, b02, ws, nch, nsc);
  kcoop<<<dim3(NWG), 256, 0, stream>>>(ws, Mb, Cb, Sb, S2b, W1b, Tgb,
                                       Yb, Pb, CPb, bar, nch);
  k4_out<<<dim3(576), 256, 0, stream>>>(x, Tgb, out);
}

// Round 13
// 224.368 us; speedup vs baseline: 1.2563x; 1.2563x over previous
//
#include <hip/hip_runtime.h>

// ---------------------------------------------------------------------------
// MRLR feature extractor, round 13: fused middle kernel with FENCE-FREE
// generation barrier (no L2 writeback: data stays XCD-local by item pinning;
// only the 8-byte flag is cross-XCD via relaxed agent-scope atomics; poll
// uses ACQUIRE (cheap L1 buffer_inv) so consumers drop stale L1 lines).
//   S1=M^2*2^-27, S2=S1^2 (M^14 = S2^3 S1):
//   Y=S1 C1; P=S2 Y; P2=S2 P; W1=proj(S2 P2)
//   TMP=M-W1 M; M2=TMP-TMP W1; C2'=C2-W1 C2; same chain -> W2; T=W1+W2
//   out = T X.
// k1: item-pinned split-K partials (r8/r11-proven).  kcoop: 104 WGs,
// 11 phases / 10 barriers.  k4: out = T X.
// ---------------------------------------------------------------------------

#define TID ((int)threadIdx.x)
typedef float4 f4;

#define SC27 (1.0f/134217728.0f)   // 2^-27
#define NWG  104

__device__ __forceinline__ f4 ld4(const float* p) { return *(const f4*)p; }
__device__ __forceinline__ void st4(float* p, f4 v) { *(f4*)p = v; }
__device__ __forceinline__ f4 f4zero() { return make_float4(0.f,0.f,0.f,0.f); }
__device__ __forceinline__ f4 add4(f4 a, f4 b){ return make_float4(a.x+b.x,a.y+b.y,a.z+b.z,a.w+b.w); }
__device__ __forceinline__ f4 sub4(f4 a, f4 b){ return make_float4(a.x-b.x,a.y-b.y,a.z-b.z,a.w-b.w); }
__device__ __forceinline__ f4 scl4(f4 a, float s){ return make_float4(a.x*s,a.y*s,a.z*s,a.w*s); }
__device__ __forceinline__ void fma4(f4& a, float s, f4 v) {
  a.x = fmaf(s,v.x,a.x); a.y = fmaf(s,v.y,a.y); a.z = fmaf(s,v.z,a.z); a.w = fmaf(s,v.w,a.w);
}
__device__ __forceinline__ float dot4(f4 a, f4 b, float acc) {
  acc = fmaf(a.x,b.x,acc); acc = fmaf(a.y,b.y,acc);
  acc = fmaf(a.z,b.z,acc); acc = fmaf(a.w,b.w,acc); return acc;
}
__device__ __forceinline__ void trimap(int t, int& ti, int& tj) {
  int rem = t; ti = 0;
  #pragma unroll
  for (int r = 0; r < 12; ++r) { int w = 12 - r; if (rem < w) { ti = r; break; } rem -= w; }
  tj = ti + rem;
}
__device__ __forceinline__ void init8(f4 acc[8][2]) {
  #pragma unroll
  for (int a = 0; a < 8; ++a) { acc[a][0] = f4zero(); acc[a][1] = f4zero(); }
}
__device__ __forceinline__ void tile8_step(f4 acc[8][2], const float* u, const float* v) {
  f4 u0 = ld4(u), u1 = ld4(u+4), v0 = ld4(v), v1 = ld4(v+4);
  float aa[8] = {u0.x,u0.y,u0.z,u0.w,u1.x,u1.y,u1.z,u1.w};
  #pragma unroll
  for (int a = 0; a < 8; ++a) { fma4(acc[a][0], aa[a], v0); fma4(acc[a][1], aa[a], v1); }
}

// ---------------------------------------------------------------------------
// Fence-free generation barrier.  bar[0]=count, bar[1]=generation (8-aligned).
// All atomics RELAXED agent-scope (coherent-point access, NO L2 writeback);
// last arriver publishes {count=0, gen+1} as ONE 64-bit atomic store (no
// reset/bump reordering); pollers use ACQUIRE (emits L1 buffer_inv only).
// Data coherence: producers/consumers of each item share an XCD L2 (item =
// wg&7 pinning); __syncthreads drains stores (vmcnt) before arrival.
// ---------------------------------------------------------------------------
__device__ __forceinline__ void gridbar(unsigned* bar, unsigned nwg) {
  __syncthreads();
  if (threadIdx.x == 0) {
    unsigned g = __hip_atomic_load(bar + 1, __ATOMIC_RELAXED, __HIP_MEMORY_SCOPE_AGENT);
    unsigned a = __hip_atomic_fetch_add(bar, 1u, __ATOMIC_RELAXED, __HIP_MEMORY_SCOPE_AGENT);
    if (a == nwg - 1u) {
      unsigned long long nv = ((unsigned long long)(g + 1u)) << 32;
      __hip_atomic_store((unsigned long long*)bar, nv, __ATOMIC_RELAXED, __HIP_MEMORY_SCOPE_AGENT);
      (void)__hip_atomic_load(bar + 1, __ATOMIC_ACQUIRE, __HIP_MEMORY_SCOPE_AGENT);
    } else {
      while (__hip_atomic_load(bar + 1, __ATOMIC_ACQUIRE, __HIP_MEMORY_SCOPE_AGENT) == g)
        __builtin_amdgcn_s_sleep(2);
    }
  }
  __syncthreads();
}

// ---------------------------------------------------------------------------
// k1 (r8/r11-proven): grid nch*8 (item = bid&7), block 512.
// ---------------------------------------------------------------------------
__global__ __launch_bounds__(512) void k1_partials(
    const float* __restrict__ x, const float* __restrict__ b01,
    const float* __restrict__ b02, float* __restrict__ part,
    int nch, int nsc) {
  __shared__ __align__(16) float Xst[48][100];
  __shared__ __align__(16) float Bs[48][52];
  __shared__ __align__(16) float red[9600];
  int bid = blockIdx.x;
  int item = bid & 7, kc = bid >> 3;
  const float* X = x + (size_t)item * 96 * 9216;
  float* base = part + (size_t)(item * nch + kc) * 9600;

  int t = TID, kh = 0, tt = 0;
  const float* ap = nullptr; const float* bp = nullptr;
  float* op = nullptr; int os = 0; bool isM = false;
  bool active = (t < 450);
  if (active) {
    kh = t / 150; tt = t % 150;
    if (tt < 78) {
      int ti, tj; trimap(tt, ti, tj);
      ap = &Xst[0][ti*8]; bp = &Xst[0][tj*8];
      op = base + tt*64; os = 8; isM = true;
    } else {
      int u = tt - 78; int i0 = (u/6)*8, c0 = (u%6)*8;
      ap = &Xst[0][i0]; bp = &Bs[0][c0];
      op = base + 4992 + i0*48 + c0; os = 48;
    }
  }

  f4 acc[8][2]; init8(acc);

  for (int sc = 0; sc < nsc; ++sc) {
    int k0 = (kc * nsc + sc) * 48;
    __syncthreads();
    for (int e = TID; e < 1152; e += 512) {
      int i = e / 12, kq = (e % 12) * 4;
      f4 v = ld4(&X[(size_t)i * 9216 + k0 + kq]);
      Xst[kq][i] = v.x; Xst[kq+1][i] = v.y; Xst[kq+2][i] = v.z; Xst[kq+3][i] = v.w;
    }
    for (int e = TID; e < 384; e += 512) {
      int kk = e / 8, cq = (e % 8) * 4;
      st4(&Bs[kk][cq], ld4(&b01[(size_t)(k0 + kk) * 32 + cq]));
    }
    for (int e = TID; e < 192; e += 512) {
      int kk = e / 4, cq = (e % 4) * 4;
      st4(&Bs[kk][32+cq], ld4(&b02[(size_t)(k0 + kk) * 16 + cq]));
    }
    __syncthreads();
    if (active) {
      int asr = 100, bsr = isM ? 100 : 52;
      const float* ar = ap + kh * asr;
      const float* br = bp + kh * bsr;
      #pragma unroll 4
      for (int kk = kh; kk < 48; kk += 3) {
        tile8_step(acc, ar, br);
        ar += 3 * asr; br += 3 * bsr;
      }
    }
  }
  __syncthreads();
  if (active && kh == 1) {
    #pragma unroll
    for (int a = 0; a < 8; ++a) { st4(&red[tt*64+a*8], acc[a][0]); st4(&red[tt*64+a*8+4], acc[a][1]); }
  }
  __syncthreads();
  if (active && kh == 0) {
    #pragma unroll
    for (int a = 0; a < 8; ++a) {
      acc[a][0] = add4(acc[a][0], ld4(&red[tt*64+a*8]));
      acc[a][1] = add4(acc[a][1], ld4(&red[tt*64+a*8+4]));
    }
  }
  __syncthreads();
  if (active && kh == 2) {
    #pragma unroll
    for (int a = 0; a < 8; ++a) { st4(&red[tt*64+a*8], acc[a][0]); st4(&red[tt*64+a*8+4], acc[a][1]); }
  }
  __syncthreads();
  if (active && kh == 0) {
    #pragma unroll
    for (int a = 0; a < 8; ++a) {
      f4 s0 = add4(acc[a][0], ld4(&red[tt*64+a*8]));
      f4 s1 = add4(acc[a][1], ld4(&red[tt*64+a*8+4]));
      st4(op + a*os, s0); st4(op + a*os + 4, s1);
    }
  }
}

// ---------------------------------------------------------------------------
// Wave-register Gauss-Jordan (stride-68 aug), verified r7-r12.
// ---------------------------------------------------------------------------
template<int R>
__device__ void gj_wave(float* aug, int lane) {
  float col[R];
  if (lane < R) {
    #pragma unroll
    for (int i = 0; i < R; ++i) col[i] = aug[i*68 + lane];
  } else {
    #pragma unroll
    for (int i = 0; i < R; ++i) col[i] = (i == lane - R) ? 1.f : 0.f;
  }
  #pragma unroll
  for (int c = 0; c < R; ++c) {
    float pc = __shfl(col[c], c);
    float rp = 1.f / pc;
    bool isc = (lane == c);
    #pragma unroll
    for (int i = 0; i < R; ++i) {
      if (i == c) continue;
      float fi = __shfl(col[i], c) * rp;
      float v = fmaf(-fi, col[c], col[i]);
      col[i] = isc ? 0.f : v;
    }
  }
  #pragma unroll
  for (int i = 0; i < R; ++i) {
    float d = __shfl(col[i], i);
    col[i] = col[i] / d;
  }
  if (lane >= R) {
    #pragma unroll
    for (int i = 0; i < R; ++i) aug[i*68 + lane] = col[i];
  }
}

// ---------------------------------------------------------------------------
// kcoop helpers (smem: Bs[96][100]@0, As[8][100]@9600, Ts[96][36]@10400;
// proj/thin overlay: Ps[96][36]@9600, Qs[96][36]@13056, aug[32][68]@16512,
// QKs[8][32]@18688; total 18944 floats = 75.8 KB)  [verified r12]
// ---------------------------------------------------------------------------
__device__ __forceinline__ void stage_full(float* Bs, const float* src, int t) {
  for (int e = t; e < 2304; e += 256) {
    int r = e / 24, cq = (e % 24) * 4;
    st4(&Bs[r*100 + cq], ld4(&src[r*96 + cq]));
  }
}
__device__ __forceinline__ void stage_slab(float* As, const float* src, int row0, int t) {
  if (t < 192) {
    int r = t / 24, cq = (t % 24) * 4;
    st4(&As[r*100 + cq], ld4(&src[(size_t)(row0 + r)*96 + cq]));
  }
}
__device__ __forceinline__ void stage_thin(float* Ts, const float* src, int istr, int nq, int t) {
  for (int e = t; e < 96*nq; e += 256) {
    int r = e / nq, cq = (e % nq) * 4;
    st4(&Ts[r*36 + cq], ld4(&src[(size_t)r*istr + cq]));
  }
}
__device__ __forceinline__ void square_slab(const float* As, const float* Bs,
    const float* Sub, float* D, float scale, int w, int t) {
  if (t < 192) {
    int rl = t / 24, jb = (t % 24) * 4;
    f4 acc = f4zero();
    #pragma unroll 8
    for (int k = 0; k < 96; ++k) fma4(acc, As[rl*100 + k], ld4(&Bs[k*100 + jb]));
    int r = w*8 + rl;
    if (Sub) acc = sub4(ld4(&Sub[r*96 + jb]), acc);
    else     acc = scl4(acc, scale);
    st4(&D[r*96 + jb], acc);
  }
}
__device__ __forceinline__ void thin_full(const float* A100, const float* Ts,
    float* To, int tos, int TW, int tsub, int t) {
  int nact = (TW == 32) ? 192 : 96;
  if (t < nact) {
    int r  = (TW == 32) ? (t >> 1) : t;
    int c0 = (TW == 32) ? (t & 1) * 16 : 0;
    f4 acc[4] = {f4zero(), f4zero(), f4zero(), f4zero()};
    #pragma unroll 4
    for (int k = 0; k < 96; ++k) {
      float a = A100[r*100 + k];
      const float* tr = &Ts[k*36 + c0];
      fma4(acc[0], a, ld4(tr));   fma4(acc[1], a, ld4(tr+4));
      fma4(acc[2], a, ld4(tr+8)); fma4(acc[3], a, ld4(tr+12));
    }
    if (tsub) {
      #pragma unroll
      for (int u = 0; u < 4; ++u) acc[u] = sub4(ld4(&Ts[r*36 + c0 + u*4]), acc[u]);
    }
    #pragma unroll
    for (int u = 0; u < 4; ++u) st4(&To[(size_t)r*tos + c0 + u*4], acc[u]);
  }
}

template<int TW>
__device__ void proj_phase(const float* Bs /*S-full staged*/, float* Ps, float* Qs,
    float* aug, float* QKs, const float* Pg, float* Wdst, const float* Wadd,
    int w, int t) {
  const int nq = TW >> 2;
  stage_thin(Ps, Pg, 32, nq, t);
  __syncthreads();
  for (int e = t; e < 96*nq; e += 256) {             // Q = S * P
    int r = e / nq, c4 = (e % nq) * 4;
    f4 acc = f4zero();
    #pragma unroll 4
    for (int k = 0; k < 96; ++k) fma4(acc, Bs[r*100 + k], ld4(&Ps[k*36 + c4]));
    st4(&Qs[r*36 + c4], acc);
  }
  __syncthreads();
  for (int e = t; e < TW*nq; e += 256) {             // Gram
    int ar = e / nq, b4 = (e % nq) * 4;
    f4 acc = f4zero();
    #pragma unroll 4
    for (int k = 0; k < 96; ++k) fma4(acc, Qs[k*36 + ar], ld4(&Qs[k*36 + b4]));
    st4(&aug[ar*68 + b4], acc);
  }
  __syncthreads();
  if (t < 2*TW) gj_wave<TW>(aug, t);
  __syncthreads();
  for (int e = t; e < TW*TW; e += 256) {             // K^T -> aug[:,0:TW]
    int m = e / TW, c = e % TW;
    aug[c*68 + m] = aug[m*68 + TW + c];
  }
  __syncthreads();
  for (int e = t; e < 8*TW; e += 256) {              // QK slab
    int rr = e / TW, c = e % TW;
    float acc = 0.f;
    #pragma unroll
    for (int m4 = 0; m4 < TW; m4 += 4)
      acc = dot4(ld4(&Qs[(w*8 + rr)*36 + m4]), ld4(&aug[c*68 + m4]), acc);
    QKs[rr*32 + c] = acc;
  }
  __syncthreads();
  if (t < 192) {                                     // W slab = QK * Q^T
    int rr = t / 24, jb = (t % 24) * 4;
    int r = w*8 + rr;
    f4 acc = f4zero();
    #pragma unroll
    for (int c4 = 0; c4 < TW; c4 += 4) {
      f4 qk = ld4(&QKs[rr*32 + c4]);
      acc.x = dot4(qk, ld4(&Qs[(jb+0)*36 + c4]), acc.x);
      acc.y = dot4(qk, ld4(&Qs[(jb+1)*36 + c4]), acc.y);
      acc.z = dot4(qk, ld4(&Qs[(jb+2)*36 + c4]), acc.z);
      acc.w = dot4(qk, ld4(&Qs[(jb+3)*36 + c4]), acc.w);
    }
    if (Wadd) acc = add4(acc, ld4(&Wadd[r*96 + jb]));
    st4(&Wdst[r*96 + jb], acc);
  }
}

// double thin apply (one WG per item): P = S*Y (LDS), P2 = S*P -> global.
// Bs holds S full; Y staged into Ps; P into Qs.
template<int TW>
__device__ void double_thin(const float* Bs, float* Ps, float* Qs,
                            float* Yi, int t) {
  const int nq = TW >> 2;
  stage_thin(Ps, Yi, 32, nq, t);
  __syncthreads();
  for (int e = t; e < 96*nq; e += 256) {
    int r = e / nq, c4 = (e % nq) * 4;
    f4 acc = f4zero();
    #pragma unroll 4
    for (int k = 0; k < 96; ++k) fma4(acc, Bs[r*100 + k], ld4(&Ps[k*36 + c4]));
    st4(&Qs[r*36 + c4], acc);
  }
  __syncthreads();
  for (int e = t; e < 96*nq; e += 256) {
    int r = e / nq, c4 = (e % nq) * 4;
    f4 acc = f4zero();
    #pragma unroll 4
    for (int k = 0; k < 96; ++k) fma4(acc, Bs[r*100 + k], ld4(&Qs[k*36 + c4]));
    st4(&Yi[r*32 + c4], acc);
  }
}

// ---------------------------------------------------------------------------
// kcoop: grid 104 (item = wg&7, w = wg>>3 in [0,13)), block 256.
// 11 phases, 10 fence-free barriers.
// ---------------------------------------------------------------------------
__global__ __launch_bounds__(256) void kcoop(
    float* __restrict__ part, float* __restrict__ Mb, float* __restrict__ Cb,
    float* __restrict__ Sb, float* __restrict__ S2b, float* __restrict__ W1b,
    float* __restrict__ Tgb, float* __restrict__ Yb,
    float* __restrict__ CPb, unsigned* __restrict__ bar, int nch) {
  __shared__ __align__(16) float smem[18944];
  float* Bs  = smem;            // [96][100]
  float* As  = smem + 9600;     // [8][100]
  float* Ts  = smem + 10400;    // [96][36]
  float* Ps  = smem + 9600;     // [96][36] (overlay; excludes As/Ts use)
  float* Qs  = smem + 13056;    // [96][36]
  float* aug = smem + 16512;    // [32][68]
  float* QKs = smem + 18688;    // [8][32]

  int wg = blockIdx.x, t = TID;
  int item = wg & 7, w = wg >> 3;
  float* Mi  = Mb  + (size_t)item * 9216;
  float* Ci  = Cb  + (size_t)item * 4608;
  float* S1i = Sb  + (size_t)item * 9216;   // S1 / TMP / S1'
  float* S2i = S2b + (size_t)item * 9216;
  float* W1i = W1b + (size_t)item * 9216;
  float* Tgi = Tgb + (size_t)item * 9216;
  float* Yi  = Yb  + (size_t)item * 3072;
  float* CPi = CPb + (size_t)item * 1536;

  // ---- A: reduce partials -> M (mirrored) + C ----
  {
    int q4 = w * 185 + t;
    if (t < 185 && q4 < 2400) {
      int off = q4 * 4;
      const float* p = part + (size_t)item * nch * 9600 + off;
      f4 s = f4zero();
      #pragma unroll 8
      for (int c = 0; c < nch; ++c) s = add4(s, ld4(p + (size_t)c * 9600));
      if (off < 4992) {
        int tile = off >> 6, ww = (off & 63) >> 2;
        int r = ww >> 1, cq = (ww & 1) * 4;
        int ti, tj; trimap(tile, ti, tj);
        int i = ti*8 + r, j = tj*8 + cq;
        st4(&Mi[i*96 + j], s);
        Mi[(j+0)*96 + i] = s.x; Mi[(j+1)*96 + i] = s.y;
        Mi[(j+2)*96 + i] = s.z; Mi[(j+3)*96 + i] = s.w;
      } else {
        st4(&Ci[off - 4992], s);
      }
    }
  }
  gridbar(bar, NWG);

  // ---- B: S1 = M^2 * 2^-27 ----
  if (w < 12) {
    stage_full(Bs, Mi, t); stage_slab(As, Mi, w*8, t);
    __syncthreads();
    square_slab(As, Bs, nullptr, S1i, SC27, w, t);
  }
  gridbar(bar, NWG);

  // ---- C: S2 = S1^2  ||  Y = S1*C1 ----
  if (w < 12) {
    stage_full(Bs, S1i, t); stage_slab(As, S1i, w*8, t);
    __syncthreads();
    square_slab(As, Bs, nullptr, S2i, 1.f, w, t);
  } else {
    stage_full(Bs, S1i, t); stage_thin(Ts, Ci, 48, 8, t);
    __syncthreads();
    thin_full(Bs, Ts, Yi, 32, 32, 0, t);
  }
  gridbar(bar, NWG);

  // ---- DE: (w==12) P = S2*Y, P2 = S2*P -> Yi ----
  if (w == 12) {
    stage_full(Bs, S2i, t);
    double_thin<32>(Bs, Ps, Qs, Yi, t);
  }
  gridbar(bar, NWG);

  // ---- F: W1 = proj(S2 * P2) ----
  if (w < 12) {
    stage_full(Bs, S2i, t);
    proj_phase<32>(Bs, Ps, Qs, aug, QKs, Yi, W1i, nullptr, w, t);
  }
  gridbar(bar, NWG);

  // ---- G: TMP = M - W1*M -> S1i  ||  C2' = C2 - W1*C2 ----
  if (w < 12) {
    stage_full(Bs, Mi, t); stage_slab(As, W1i, w*8, t);
    __syncthreads();
    square_slab(As, Bs, Mi, S1i, 1.f, w, t);
  } else {
    stage_full(Bs, W1i, t); stage_thin(Ts, Ci + 32, 48, 4, t);
    __syncthreads();
    thin_full(Bs, Ts, CPi, 16, 16, 1, t);
  }
  gridbar(bar, NWG);

  // ---- H: M2 = TMP - TMP*W1 -> Mb ----
  if (w < 12) {
    stage_full(Bs, W1i, t); stage_slab(As, S1i, w*8, t);
    __syncthreads();
    square_slab(As, Bs, S1i, Mi, 1.f, w, t);
  }
  gridbar(bar, NWG);

  // ---- I: S1' = M2^2 * 2^-27 ----
  if (w < 12) {
    stage_full(Bs, Mi, t); stage_slab(As, Mi, w*8, t);
    __syncthreads();
    square_slab(As, Bs, nullptr, S1i, SC27, w, t);
  }
  gridbar(bar, NWG);

  // ---- J: S2' = S1'^2  ||  Y = S1'*C2' ----
  if (w < 12) {
    stage_full(Bs, S1i, t); stage_slab(As, S1i, w*8, t);
    __syncthreads();
    square_slab(As, Bs, nullptr, S2i, 1.f, w, t);
  } else {
    stage_full(Bs, S1i, t); stage_thin(Ts, CPi, 16, 4, t);
    __syncthreads();
    thin_full(Bs, Ts, Yi, 32, 16, 0, t);
  }
  gridbar(bar, NWG);

  // ---- KL: (w==12) P = S2'*Y, P2 = S2'*P -> Yi ----
  if (w == 12) {
    stage_full(Bs, S2i, t);
    double_thin<16>(Bs, Ps, Qs, Yi, t);
  }
  gridbar(bar, NWG);

  // ---- M: Tg = W1 + proj(S2' * P2) ----
  if (w < 12) {
    stage_full(Bs, S2i, t);
    proj_phase<16>(Bs, Ps, Qs, aug, QKs, Yi, Tgi, W1i, w, t);
  }
}

// ---------------------------------------------------------------------------
// k4: out = T @ X.  grid 576 (item = bid&7), block 256.
// ---------------------------------------------------------------------------
__global__ __launch_bounds__(256) void k4_out(
    const float* __restrict__ x, const float* __restrict__ Tgg,
    float* __restrict__ out) {
  __shared__ __align__(16) float Tt[96][100];
  int bid = blockIdx.x;
  int item = bid & 7, jb = bid >> 3;
  const float* Tg = Tgg + (size_t)item * 9216;
  for (int e = TID * 4; e < 9216; e += 1024) {
    f4 v = ld4(&Tg[e]);
    int i = e / 96, k = e % 96;
    Tt[k][i] = v.x; Tt[k+1][i] = v.y; Tt[k+2][i] = v.z; Tt[k+3][i] = v.w;
  }
  __syncthreads();

  int jq = (TID % 32) * 4, ig = TID / 32;
  int i0 = ig * 12;
  int col = jb * 128 + jq;
  const float* X = x + (size_t)item * 96 * 9216;
  f4 acc[12];
  #pragma unroll
  for (int a = 0; a < 12; ++a) acc[a] = f4zero();

  for (int k = 0; k < 96; ++k) {
    f4 xv = ld4(&X[(size_t)k * 9216 + col]);
    f4 t0 = ld4(&Tt[k][i0]), t1 = ld4(&Tt[k][i0+4]), t2 = ld4(&Tt[k][i0+8]);
    fma4(acc[0], t0.x, xv); fma4(acc[1], t0.y, xv); fma4(acc[2], t0.z, xv); fma4(acc[3], t0.w, xv);
    fma4(acc[4], t1.x, xv); fma4(acc[5], t1.y, xv); fma4(acc[6], t1.z, xv); fma4(acc[7], t1.w, xv);
    fma4(acc[8], t2.x, xv); fma4(acc[9], t2.y, xv); fma4(acc[10], t2.z, xv); fma4(acc[11], t2.w, xv);
  }
  float* O = out + (size_t)item * 96 * 9216;
  #pragma unroll
  for (int a = 0; a < 12; ++a) st4(&O[(size_t)(i0 + a) * 9216 + col], acc[a]);
}

// ---------------------------------------------------------------------------
extern "C" void kernel_launch(void* const* d_in, const int* in_sizes, int n_in,
                              void* d_out, int out_size, void* d_ws, size_t ws_size,
                              hipStream_t stream) {
  (void)in_sizes; (void)n_in; (void)out_size;
  const float* x   = (const float*)d_in[0];
  const float* b01 = (const float*)d_in[2];
  const float* b02 = (const float*)d_in[4];
  float* out = (float*)d_out;
  float* ws  = (float*)d_ws;

  const size_t EXTRA = 73728ull*5 + 36864 + 24576*2 + 12288 + 16;
  int nch = (ws_size >= ((size_t)64*8*9600 + EXTRA) * sizeof(float)) ? 64 : 32;
  int nsc = 9216 / nch / 48;

  float* Mb  = ws + (size_t)nch * 8 * 9600;
  float* Cb  = Mb  + 73728;
  float* Sb  = Cb  + 36864;
  float* S2b = Sb  + 73728;
  float* W1b = S2b + 73728;
  float* Tgb = W1b + 73728;
  float* Yb  = Tgb + 73728;
  float* Pb  = Yb  + 24576;     // unused (kept for layout stability)
  float* CPb = Pb  + 24576;
  unsigned* bar = (unsigned*)(CPb + 12288);

  hipMemsetAsync((void*)bar, 0, 16, stream);
  k1_partials<<<dim3(nch*8), 512, 0, stream>>>(x, b01, b02, ws, nch, nsc);
  kcoop<<<dim3(NWG), 256, 0, stream>>>(ws, Mb, Cb, Sb, S2b, W1b, Tgb,
                                       Yb, CPb, bar, nch);
  k4_out<<<dim3(576), 256, 0, stream>>>(x, Tgb, out);
}

// Round 14
// 177.888 us; speedup vs baseline: 1.5845x; 1.2613x over previous
//
#include <hip/hip_runtime.h>

// ---------------------------------------------------------------------------
// MRLR feature extractor, round 14: r11 multi-kernel structure, with the
// thin-apply chain folded into the proj kernel (redundant per-WG compute).
//   S1=M^2*2^-27, S2=S1^2;  W1=proj(S2*(S2*(S2*(S1*C1))))
//   TMP=M-W1 M; M2=TMP-TMP W1; C2'=C2-W1 C2; same chain -> W2; T=W1+W2
//   out = T X.
// 11 dispatches: k1, k2, S1, {S2||Y}, proj1, {TMP||C2'}, M2, S1', {S2'||Y'},
// proj2, k4.  All item-pinned (item = bid&7 -> XCD-local L2).
// ---------------------------------------------------------------------------

#define TID ((int)threadIdx.x)
typedef float4 f4;

#define SC27 (1.0f/134217728.0f)   // 2^-27

__device__ __forceinline__ f4 ld4(const float* p) { return *(const f4*)p; }
__device__ __forceinline__ void st4(float* p, f4 v) { *(f4*)p = v; }
__device__ __forceinline__ f4 f4zero() { return make_float4(0.f,0.f,0.f,0.f); }
__device__ __forceinline__ f4 add4(f4 a, f4 b){ return make_float4(a.x+b.x,a.y+b.y,a.z+b.z,a.w+b.w); }
__device__ __forceinline__ f4 sub4(f4 a, f4 b){ return make_float4(a.x-b.x,a.y-b.y,a.z-b.z,a.w-b.w); }
__device__ __forceinline__ f4 scl4(f4 a, float s){ return make_float4(a.x*s,a.y*s,a.z*s,a.w*s); }
__device__ __forceinline__ void fma4(f4& a, float s, f4 v) {
  a.x = fmaf(s,v.x,a.x); a.y = fmaf(s,v.y,a.y); a.z = fmaf(s,v.z,a.z); a.w = fmaf(s,v.w,a.w);
}
__device__ __forceinline__ float dot4(f4 a, f4 b, float acc) {
  acc = fmaf(a.x,b.x,acc); acc = fmaf(a.y,b.y,acc);
  acc = fmaf(a.z,b.z,acc); acc = fmaf(a.w,b.w,acc); return acc;
}
__device__ __forceinline__ void trimap(int t, int& ti, int& tj) {
  int rem = t; ti = 0;
  #pragma unroll
  for (int r = 0; r < 12; ++r) { int w = 12 - r; if (rem < w) { ti = r; break; } rem -= w; }
  tj = ti + rem;
}
__device__ __forceinline__ void init8(f4 acc[8][2]) {
  #pragma unroll
  for (int a = 0; a < 8; ++a) { acc[a][0] = f4zero(); acc[a][1] = f4zero(); }
}
__device__ __forceinline__ void tile8_step(f4 acc[8][2], const float* u, const float* v) {
  f4 u0 = ld4(u), u1 = ld4(u+4), v0 = ld4(v), v1 = ld4(v+4);
  float aa[8] = {u0.x,u0.y,u0.z,u0.w,u1.x,u1.y,u1.z,u1.w};
  #pragma unroll
  for (int a = 0; a < 8; ++a) { fma4(acc[a][0], aa[a], v0); fma4(acc[a][1], aa[a], v1); }
}

// ---------------------------------------------------------------------------
// k1 (r8/r11-proven): grid nch*8 (item = bid&7), block 512.
// ---------------------------------------------------------------------------
__global__ __launch_bounds__(512) void k1_partials(
    const float* __restrict__ x, const float* __restrict__ b01,
    const float* __restrict__ b02, float* __restrict__ part,
    int nch, int nsc) {
  __shared__ __align__(16) float Xst[48][100];
  __shared__ __align__(16) float Bs[48][52];
  __shared__ __align__(16) float red[9600];
  int bid = blockIdx.x;
  int item = bid & 7, kc = bid >> 3;
  const float* X = x + (size_t)item * 96 * 9216;
  float* base = part + (size_t)(item * nch + kc) * 9600;

  int t = TID, kh = 0, tt = 0;
  const float* ap = nullptr; const float* bp = nullptr;
  float* op = nullptr; int os = 0; bool isM = false;
  bool active = (t < 450);
  if (active) {
    kh = t / 150; tt = t % 150;
    if (tt < 78) {
      int ti, tj; trimap(tt, ti, tj);
      ap = &Xst[0][ti*8]; bp = &Xst[0][tj*8];
      op = base + tt*64; os = 8; isM = true;
    } else {
      int u = tt - 78; int i0 = (u/6)*8, c0 = (u%6)*8;
      ap = &Xst[0][i0]; bp = &Bs[0][c0];
      op = base + 4992 + i0*48 + c0; os = 48;
    }
  }

  f4 acc[8][2]; init8(acc);

  for (int sc = 0; sc < nsc; ++sc) {
    int k0 = (kc * nsc + sc) * 48;
    __syncthreads();
    for (int e = TID; e < 1152; e += 512) {
      int i = e / 12, kq = (e % 12) * 4;
      f4 v = ld4(&X[(size_t)i * 9216 + k0 + kq]);
      Xst[kq][i] = v.x; Xst[kq+1][i] = v.y; Xst[kq+2][i] = v.z; Xst[kq+3][i] = v.w;
    }
    for (int e = TID; e < 384; e += 512) {
      int kk = e / 8, cq = (e % 8) * 4;
      st4(&Bs[kk][cq], ld4(&b01[(size_t)(k0 + kk) * 32 + cq]));
    }
    for (int e = TID; e < 192; e += 512) {
      int kk = e / 4, cq = (e % 4) * 4;
      st4(&Bs[kk][32+cq], ld4(&b02[(size_t)(k0 + kk) * 16 + cq]));
    }
    __syncthreads();
    if (active) {
      int asr = 100, bsr = isM ? 100 : 52;
      const float* ar = ap + kh * asr;
      const float* br = bp + kh * bsr;
      #pragma unroll 4
      for (int kk = kh; kk < 48; kk += 3) {
        tile8_step(acc, ar, br);
        ar += 3 * asr; br += 3 * bsr;
      }
    }
  }
  __syncthreads();
  if (active && kh == 1) {
    #pragma unroll
    for (int a = 0; a < 8; ++a) { st4(&red[tt*64+a*8], acc[a][0]); st4(&red[tt*64+a*8+4], acc[a][1]); }
  }
  __syncthreads();
  if (active && kh == 0) {
    #pragma unroll
    for (int a = 0; a < 8; ++a) {
      acc[a][0] = add4(acc[a][0], ld4(&red[tt*64+a*8]));
      acc[a][1] = add4(acc[a][1], ld4(&red[tt*64+a*8+4]));
    }
  }
  __syncthreads();
  if (active && kh == 2) {
    #pragma unroll
    for (int a = 0; a < 8; ++a) { st4(&red[tt*64+a*8], acc[a][0]); st4(&red[tt*64+a*8+4], acc[a][1]); }
  }
  __syncthreads();
  if (active && kh == 0) {
    #pragma unroll
    for (int a = 0; a < 8; ++a) {
      f4 s0 = add4(acc[a][0], ld4(&red[tt*64+a*8]));
      f4 s1 = add4(acc[a][1], ld4(&red[tt*64+a*8+4]));
      st4(op + a*os, s0); st4(op + a*os + 4, s1);
    }
  }
}

// ---------------------------------------------------------------------------
// k2: reduce nch partials -> M unpacked (mirrored) + C.  grid 160 x 128.
// ---------------------------------------------------------------------------
__global__ __launch_bounds__(128) void k2_reduce(
    const float* __restrict__ part, float* __restrict__ Mb,
    float* __restrict__ Cb, int nch) {
  int bid = blockIdx.x;
  int item = bid & 7, chunk = bid >> 3;
  if (TID >= 120) return;
  int q4 = chunk * 120 + TID;             // < 2400
  int off = q4 * 4;
  const float* p = part + (size_t)item * nch * 9600 + off;
  f4 s = f4zero();
  #pragma unroll 8
  for (int c = 0; c < nch; ++c) s = add4(s, ld4(p + (size_t)c * 9600));
  if (off < 4992) {
    int tile = off >> 6, w = (off & 63) >> 2;
    int r = w >> 1, cq = (w & 1) * 4;
    int ti, tj; trimap(tile, ti, tj);
    int i = ti*8 + r, j = tj*8 + cq;
    float* Mi = Mb + (size_t)item * 9216;
    st4(&Mi[i*96 + j], s);
    Mi[(j+0)*96 + i] = s.x; Mi[(j+1)*96 + i] = s.y;
    Mi[(j+2)*96 + i] = s.z; Mi[(j+3)*96 + i] = s.w;
  } else {
    st4(&Cb[(size_t)item * 4608 + (off - 4992)], s);
  }
}

// ---------------------------------------------------------------------------
// kw_phase (r11-proven): LDS-staged wide GEMM phase.  grid nw*8, block 256.
// ---------------------------------------------------------------------------
__global__ __launch_bounds__(256) void kw_phase(
    const float* __restrict__ Ag, const float* __restrict__ Bg,
    const float* __restrict__ Subg, float* __restrict__ Dg, float scale,
    const float* __restrict__ Tin, int ti_istr, int tis, int tsub,
    float* __restrict__ Tout, int to_istr, int tos, int TW) {
  __shared__ __align__(16) float Bs[96][100];   // B-full | A-full
  __shared__ __align__(16) float As[8][100];    // A-slab (square)
  __shared__ __align__(16) float Ts[96][36];    // Tin (thin)
  int bid = blockIdx.x;
  int item = bid & 7, w = bid >> 3, t = TID;
  const float* A = Ag + (size_t)item * 9216;

  if (w < 12) {
    const float* B = Bg + (size_t)item * 9216;
    for (int e = t; e < 2304; e += 256) {            // stage B-full
      int r = e / 24, cq = (e % 24) * 4;
      st4(&Bs[r][cq], ld4(&B[r*96 + cq]));
    }
    if (t < 192) {                                   // stage A-slab
      int r = t / 24, cq = (t % 24) * 4;
      st4(&As[r][cq], ld4(&A[(size_t)(w*8 + r)*96 + cq]));
    }
    __syncthreads();
    if (t < 192) {
      int rl = t / 24, jb = (t % 24) * 4;
      f4 acc = f4zero();
      #pragma unroll 8
      for (int k = 0; k < 96; ++k) fma4(acc, As[rl][k], ld4(&Bs[k][jb]));
      int r = w*8 + rl;
      if (Subg) acc = sub4(ld4(&Subg[(size_t)item*9216 + r*96 + jb]), acc);
      else      acc = scl4(acc, scale);
      st4(&Dg[(size_t)item*9216 + r*96 + jb], acc);
    }
  } else {
    for (int e = t; e < 2304; e += 256) {            // stage A-full
      int r = e / 24, cq = (e % 24) * 4;
      st4(&Bs[r][cq], ld4(&A[r*96 + cq]));
    }
    int nq = TW >> 2;
    const float* Ti = Tin + (size_t)item * ti_istr;
    for (int e = t; e < 96*nq; e += 256) {           // stage Tin
      int r = e / nq, cq = (e % nq) * 4;
      st4(&Ts[r][cq], ld4(&Ti[(size_t)r * tis + cq]));
    }
    __syncthreads();
    int nact = (TW == 32) ? 192 : 96;
    if (t < nact) {
      int r  = (TW == 32) ? (t >> 1) : t;
      int c0 = (TW == 32) ? (t & 1) * 16 : 0;
      f4 acc[4] = {f4zero(), f4zero(), f4zero(), f4zero()};
      #pragma unroll 4
      for (int k = 0; k < 96; ++k) {
        float a = Bs[r][k];
        const float* tr = &Ts[k][c0];
        fma4(acc[0], a, ld4(tr));   fma4(acc[1], a, ld4(tr+4));
        fma4(acc[2], a, ld4(tr+8)); fma4(acc[3], a, ld4(tr+12));
      }
      if (tsub) {
        #pragma unroll
        for (int u = 0; u < 4; ++u) acc[u] = sub4(ld4(&Ts[r][c0 + u*4]), acc[u]);
      }
      float* To = Tout + (size_t)item * to_istr;
      #pragma unroll
      for (int u = 0; u < 4; ++u) st4(&To[(size_t)r * tos + c0 + u*4], acc[u]);
    }
  }
}

// ---------------------------------------------------------------------------
// Wave-register Gauss-Jordan (stride-68 aug), verified r7-r13.
// ---------------------------------------------------------------------------
template<int R>
__device__ void gj_wave(float* aug, int lane) {
  float col[R];
  if (lane < R) {
    #pragma unroll
    for (int i = 0; i < R; ++i) col[i] = aug[i*68 + lane];
  } else {
    #pragma unroll
    for (int i = 0; i < R; ++i) col[i] = (i == lane - R) ? 1.f : 0.f;
  }
  #pragma unroll
  for (int c = 0; c < R; ++c) {
    float pc = __shfl(col[c], c);
    float rp = 1.f / pc;
    bool isc = (lane == c);
    #pragma unroll
    for (int i = 0; i < R; ++i) {
      if (i == c) continue;
      float fi = __shfl(col[i], c) * rp;
      float v = fmaf(-fi, col[c], col[i]);
      col[i] = isc ? 0.f : v;
    }
  }
  #pragma unroll
  for (int i = 0; i < R; ++i) {
    float d = __shfl(col[i], i);
    col[i] = col[i] / d;
  }
  if (lane >= R) {
    #pragma unroll
    for (int i = 0; i < R; ++i) aug[i*68 + lane] = col[i];
  }
}

// ---------------------------------------------------------------------------
// kWproj3<TW,MODE>: staged S; chain P=S*Y, P2=S*P, Q=S*P2 in LDS (redundant
// per WG, ping-pong buffers); Gram -> wave-GJ -> QK slab -> W slab.
// grid 96 (item = bid&7, w = bid>>3), block 256.
// MODE 1: W -> W1g.  MODE 2: Tg = W1g + W.
// smem: Bs[96][100]@0, Ta[96][36]@9600, Tb[96][36]@13056, aug[32][68]@16512,
// QKs[8][32]@18688 -> 18944 floats (75.8 KB).
// ---------------------------------------------------------------------------
template<int TW, int MODE>
__global__ __launch_bounds__(256) void kWproj3(
    const float* __restrict__ Sg, const float* __restrict__ Yg,
    float* __restrict__ W1g, float* __restrict__ Tgg) {
  __shared__ __align__(16) float smem[18944];
  float* Bs  = smem;            // [96][100]
  float* Ta  = smem + 9600;     // [96][36]
  float* Tb  = smem + 13056;    // [96][36]
  float* aug = smem + 16512;    // [32][68]
  float* QKs = smem + 18688;    // [8][32]

  int bid = blockIdx.x;
  int item = bid & 7, w = bid >> 3, t = TID;
  const float* S = Sg + (size_t)item * 9216;
  const float* Y = Yg + (size_t)item * 3072;
  float* W1 = W1g + (size_t)item * 9216;
  float* Tg = Tgg + (size_t)item * 9216;
  const int nq = TW >> 2;

  // s0: stage S full + Y
  for (int e = t; e < 2304; e += 256) {
    int r = e / 24, cq = (e % 24) * 4;
    st4(&Bs[r*100 + cq], ld4(&S[r*96 + cq]));
  }
  for (int e = t; e < 96*nq; e += 256) {
    int r = e / nq, cq = (e % nq) * 4;
    st4(&Ta[r*36 + cq], ld4(&Y[r*32 + cq]));
  }
  __syncthreads();

  // s1-s3: Tb = S*Ta; Ta = S*Tb; Tb = S*Ta   (P, P2, Q)
  #pragma unroll
  for (int pass = 0; pass < 3; ++pass) {
    const float* src = (pass & 1) ? Tb : Ta;
    float* dst       = (pass & 1) ? Ta : Tb;
    for (int e = t; e < 96*nq; e += 256) {
      int r = e / nq, c4 = (e % nq) * 4;
      f4 acc = f4zero();
      #pragma unroll 4
      for (int k = 0; k < 96; ++k) fma4(acc, Bs[r*100 + k], ld4(&src[k*36 + c4]));
      st4(&dst[r*36 + c4], acc);
    }
    __syncthreads();
  }
  // Q now in Tb.

  // s4: Gram = Q^T Q -> aug[:,0:TW]
  for (int e = t; e < TW*nq; e += 256) {
    int ar = e / nq, b4 = (e % nq) * 4;
    f4 acc = f4zero();
    #pragma unroll 4
    for (int k = 0; k < 96; ++k) fma4(acc, Tb[k*36 + ar], ld4(&Tb[k*36 + b4]));
    st4(&aug[ar*68 + b4], acc);
  }
  __syncthreads();

  // s5: wave-GJ -> K in aug[:,TW:2TW]; K^T -> aug[:,0:TW]
  if (t < 2*TW) gj_wave<TW>(aug, t);
  __syncthreads();
  for (int e = t; e < TW*TW; e += 256) {
    int m = e / TW, c = e % TW;
    aug[c*68 + m] = aug[m*68 + TW + c];
  }
  __syncthreads();

  // s6: QK slab (rows w*8..w*8+8)
  for (int e = t; e < 8*TW; e += 256) {
    int rr = e / TW, c = e % TW;
    float acc = 0.f;
    #pragma unroll
    for (int m4 = 0; m4 < TW; m4 += 4)
      acc = dot4(ld4(&Tb[(w*8 + rr)*36 + m4]), ld4(&aug[c*68 + m4]), acc);
    QKs[rr*32 + c] = acc;
  }
  __syncthreads();

  // s7: W slab = QK * Q^T
  if (t < 192) {
    int rr = t / 24, jb = (t % 24) * 4;
    int r = w*8 + rr;
    f4 acc = f4zero();
    #pragma unroll
    for (int c4 = 0; c4 < TW; c4 += 4) {
      f4 qk = ld4(&QKs[rr*32 + c4]);
      acc.x = dot4(qk, ld4(&Tb[(jb+0)*36 + c4]), acc.x);
      acc.y = dot4(qk, ld4(&Tb[(jb+1)*36 + c4]), acc.y);
      acc.z = dot4(qk, ld4(&Tb[(jb+2)*36 + c4]), acc.z);
      acc.w = dot4(qk, ld4(&Tb[(jb+3)*36 + c4]), acc.w);
    }
    if (MODE == 1) st4(&W1[r*96 + jb], acc);
    else           st4(&Tg[r*96 + jb], add4(acc, ld4(&W1[r*96 + jb])));
  }
}

// ---------------------------------------------------------------------------
// k4: out = T @ X.  grid 576 (item = bid&7), block 256.
// ---------------------------------------------------------------------------
__global__ __launch_bounds__(256) void k4_out(
    const float* __restrict__ x, const float* __restrict__ Tgg,
    float* __restrict__ out) {
  __shared__ __align__(16) float Tt[96][100];
  int bid = blockIdx.x;
  int item = bid & 7, jb = bid >> 3;
  const float* Tg = Tgg + (size_t)item * 9216;
  for (int e = TID * 4; e < 9216; e += 1024) {
    f4 v = ld4(&Tg[e]);
    int i = e / 96, k = e % 96;
    Tt[k][i] = v.x; Tt[k+1][i] = v.y; Tt[k+2][i] = v.z; Tt[k+3][i] = v.w;
  }
  __syncthreads();

  int jq = (TID % 32) * 4, ig = TID / 32;
  int i0 = ig * 12;
  int col = jb * 128 + jq;
  const float* X = x + (size_t)item * 96 * 9216;
  f4 acc[12];
  #pragma unroll
  for (int a = 0; a < 12; ++a) acc[a] = f4zero();

  for (int k = 0; k < 96; ++k) {
    f4 xv = ld4(&X[(size_t)k * 9216 + col]);
    f4 t0 = ld4(&Tt[k][i0]), t1 = ld4(&Tt[k][i0+4]), t2 = ld4(&Tt[k][i0+8]);
    fma4(acc[0], t0.x, xv); fma4(acc[1], t0.y, xv); fma4(acc[2], t0.z, xv); fma4(acc[3], t0.w, xv);
    fma4(acc[4], t1.x, xv); fma4(acc[5], t1.y, xv); fma4(acc[6], t1.z, xv); fma4(acc[7], t1.w, xv);
    fma4(acc[8], t2.x, xv); fma4(acc[9], t2.y, xv); fma4(acc[10], t2.z, xv); fma4(acc[11], t2.w, xv);
  }
  float* O = out + (size_t)item * 96 * 9216;
  #pragma unroll
  for (int a = 0; a < 12; ++a) st4(&O[(size_t)(i0 + a) * 9216 + col], acc[a]);
}

// ---------------------------------------------------------------------------
extern "C" void kernel_launch(void* const* d_in, const int* in_sizes, int n_in,
                              void* d_out, int out_size, void* d_ws, size_t ws_size,
                              hipStream_t stream) {
  (void)in_sizes; (void)n_in; (void)out_size;
  const float* x   = (const float*)d_in[0];
  const float* b01 = (const float*)d_in[2];
  const float* b02 = (const float*)d_in[4];
  float* out = (float*)d_out;
  float* ws  = (float*)d_ws;

  const size_t EXTRA = 73728ull*5 + 36864 + 24576 + 12288;
  int nch = (ws_size >= ((size_t)64*8*9600 + EXTRA) * sizeof(float)) ? 64 : 32;
  int nsc = 9216 / nch / 48;

  float* Mb  = ws + (size_t)nch * 8 * 9600;
  float* Cb  = Mb  + 73728;
  float* Sb  = Cb  + 36864;    // S1 / TMP / S1'
  float* S2b = Sb  + 73728;
  float* W1b = S2b + 73728;
  float* Tgb = W1b + 73728;
  float* Yb  = Tgb + 73728;
  float* CPb = Yb  + 24576;

  k1_partials<<<dim3(nch*8), 512, 0, stream>>>(x, b01, b02, ws, nch, nsc);
  k2_reduce<<<dim3(160), 128, 0, stream>>>(ws, Mb, Cb, nch);

  // partition 1
  kw_phase<<<dim3(96),256,0,stream>>>(Mb, Mb, nullptr, Sb, SC27,
      nullptr,0,0,0, nullptr,0,0, 0);                                   // S1 = M^2*s
  kw_phase<<<dim3(104),256,0,stream>>>(Sb, Sb, nullptr, S2b, 1.f,
      Cb,4608,48,0, Yb,3072,32, 32);                                    // S2 ; Y = S1*C1
  kWproj3<32,1><<<dim3(96),256,0,stream>>>(S2b, Yb, W1b, Tgb);          // W1 = proj(S2^3 Y)

  // M2 construction
  kw_phase<<<dim3(104),256,0,stream>>>(W1b, Mb, Mb, Sb, 1.f,
      Cb+32,4608,48,1, CPb,1536,16, 16);                                // TMP = M - W1*M ; C2'
  kw_phase<<<dim3(96),256,0,stream>>>(Sb, W1b, Sb, Mb, 1.f,
      nullptr,0,0,0, nullptr,0,0, 0);                                   // M2 = TMP - TMP*W1

  // partition 2
  kw_phase<<<dim3(96),256,0,stream>>>(Mb, Mb, nullptr, Sb, SC27,
      nullptr,0,0,0, nullptr,0,0, 0);                                   // S1' = M2^2*s
  kw_phase<<<dim3(104),256,0,stream>>>(Sb, Sb, nullptr, S2b, 1.f,
      CPb,1536,16,0, Yb,3072,32, 16);                                   // S2' ; Y' = S1'*C2'
  kWproj3<16,2><<<dim3(96),256,0,stream>>>(S2b, Yb, W1b, Tgb);          // Tg = W1 + proj(S2'^3 Y')

  k4_out<<<dim3(576), 256, 0, stream>>>(x, Tgb, out);
}

// Round 15
// 174.671 us; speedup vs baseline: 1.6137x; 1.0184x over previous
//
#include <hip/hip_runtime.h>

// ---------------------------------------------------------------------------
// MRLR feature extractor, round 15: r14 structure; kWproj3 passes restructured
// with k-major S staging (St[k][r]) -> 2x b128 per k for a 4x4 register tile
// (4x fewer LDS instructions than r14's scalar+vector pair per output).
//   S1=M^2*2^-27, S2=S1^2;  W1=proj(S2*(S2*(S2*(S1*C1))))
//   TMP=M-W1 M; M2=TMP-TMP W1; C2'=C2-W1 C2; same chain -> W2; T=W1+W2
//   out = T X.
// 11 dispatches, all item-pinned (item = bid&7 -> XCD-local L2).
// ---------------------------------------------------------------------------

#define TID ((int)threadIdx.x)
typedef float4 f4;

#define SC27 (1.0f/134217728.0f)   // 2^-27

__device__ __forceinline__ f4 ld4(const float* p) { return *(const f4*)p; }
__device__ __forceinline__ void st4(float* p, f4 v) { *(f4*)p = v; }
__device__ __forceinline__ f4 f4zero() { return make_float4(0.f,0.f,0.f,0.f); }
__device__ __forceinline__ f4 add4(f4 a, f4 b){ return make_float4(a.x+b.x,a.y+b.y,a.z+b.z,a.w+b.w); }
__device__ __forceinline__ f4 sub4(f4 a, f4 b){ return make_float4(a.x-b.x,a.y-b.y,a.z-b.z,a.w-b.w); }
__device__ __forceinline__ f4 scl4(f4 a, float s){ return make_float4(a.x*s,a.y*s,a.z*s,a.w*s); }
__device__ __forceinline__ void fma4(f4& a, float s, f4 v) {
  a.x = fmaf(s,v.x,a.x); a.y = fmaf(s,v.y,a.y); a.z = fmaf(s,v.z,a.z); a.w = fmaf(s,v.w,a.w);
}
__device__ __forceinline__ float dot4(f4 a, f4 b, float acc) {
  acc = fmaf(a.x,b.x,acc); acc = fmaf(a.y,b.y,acc);
  acc = fmaf(a.z,b.z,acc); acc = fmaf(a.w,b.w,acc); return acc;
}
__device__ __forceinline__ void trimap(int t, int& ti, int& tj) {
  int rem = t; ti = 0;
  #pragma unroll
  for (int r = 0; r < 12; ++r) { int w = 12 - r; if (rem < w) { ti = r; break; } rem -= w; }
  tj = ti + rem;
}
__device__ __forceinline__ void init8(f4 acc[8][2]) {
  #pragma unroll
  for (int a = 0; a < 8; ++a) { acc[a][0] = f4zero(); acc[a][1] = f4zero(); }
}
__device__ __forceinline__ void tile8_step(f4 acc[8][2], const float* u, const float* v) {
  f4 u0 = ld4(u), u1 = ld4(u+4), v0 = ld4(v), v1 = ld4(v+4);
  float aa[8] = {u0.x,u0.y,u0.z,u0.w,u1.x,u1.y,u1.z,u1.w};
  #pragma unroll
  for (int a = 0; a < 8; ++a) { fma4(acc[a][0], aa[a], v0); fma4(acc[a][1], aa[a], v1); }
}

// ---------------------------------------------------------------------------
// k1 (r8/r11-proven): grid nch*8 (item = bid&7), block 512.
// ---------------------------------------------------------------------------
__global__ __launch_bounds__(512) void k1_partials(
    const float* __restrict__ x, const float* __restrict__ b01,
    const float* __restrict__ b02, float* __restrict__ part,
    int nch, int nsc) {
  __shared__ __align__(16) float Xst[48][100];
  __shared__ __align__(16) float Bs[48][52];
  __shared__ __align__(16) float red[9600];
  int bid = blockIdx.x;
  int item = bid & 7, kc = bid >> 3;
  const float* X = x + (size_t)item * 96 * 9216;
  float* base = part + (size_t)(item * nch + kc) * 9600;

  int t = TID, kh = 0, tt = 0;
  const float* ap = nullptr; const float* bp = nullptr;
  float* op = nullptr; int os = 0; bool isM = false;
  bool active = (t < 450);
  if (active) {
    kh = t / 150; tt = t % 150;
    if (tt < 78) {
      int ti, tj; trimap(tt, ti, tj);
      ap = &Xst[0][ti*8]; bp = &Xst[0][tj*8];
      op = base + tt*64; os = 8; isM = true;
    } else {
      int u = tt - 78; int i0 = (u/6)*8, c0 = (u%6)*8;
      ap = &Xst[0][i0]; bp = &Bs[0][c0];
      op = base + 4992 + i0*48 + c0; os = 48;
    }
  }

  f4 acc[8][2]; init8(acc);

  for (int sc = 0; sc < nsc; ++sc) {
    int k0 = (kc * nsc + sc) * 48;
    __syncthreads();
    for (int e = TID; e < 1152; e += 512) {
      int i = e / 12, kq = (e % 12) * 4;
      f4 v = ld4(&X[(size_t)i * 9216 + k0 + kq]);
      Xst[kq][i] = v.x; Xst[kq+1][i] = v.y; Xst[kq+2][i] = v.z; Xst[kq+3][i] = v.w;
    }
    for (int e = TID; e < 384; e += 512) {
      int kk = e / 8, cq = (e % 8) * 4;
      st4(&Bs[kk][cq], ld4(&b01[(size_t)(k0 + kk) * 32 + cq]));
    }
    for (int e = TID; e < 192; e += 512) {
      int kk = e / 4, cq = (e % 4) * 4;
      st4(&Bs[kk][32+cq], ld4(&b02[(size_t)(k0 + kk) * 16 + cq]));
    }
    __syncthreads();
    if (active) {
      int asr = 100, bsr = isM ? 100 : 52;
      const float* ar = ap + kh * asr;
      const float* br = bp + kh * bsr;
      #pragma unroll 4
      for (int kk = kh; kk < 48; kk += 3) {
        tile8_step(acc, ar, br);
        ar += 3 * asr; br += 3 * bsr;
      }
    }
  }
  __syncthreads();
  if (active && kh == 1) {
    #pragma unroll
    for (int a = 0; a < 8; ++a) { st4(&red[tt*64+a*8], acc[a][0]); st4(&red[tt*64+a*8+4], acc[a][1]); }
  }
  __syncthreads();
  if (active && kh == 0) {
    #pragma unroll
    for (int a = 0; a < 8; ++a) {
      acc[a][0] = add4(acc[a][0], ld4(&red[tt*64+a*8]));
      acc[a][1] = add4(acc[a][1], ld4(&red[tt*64+a*8+4]));
    }
  }
  __syncthreads();
  if (active && kh == 2) {
    #pragma unroll
    for (int a = 0; a < 8; ++a) { st4(&red[tt*64+a*8], acc[a][0]); st4(&red[tt*64+a*8+4], acc[a][1]); }
  }
  __syncthreads();
  if (active && kh == 0) {
    #pragma unroll
    for (int a = 0; a < 8; ++a) {
      f4 s0 = add4(acc[a][0], ld4(&red[tt*64+a*8]));
      f4 s1 = add4(acc[a][1], ld4(&red[tt*64+a*8+4]));
      st4(op + a*os, s0); st4(op + a*os + 4, s1);
    }
  }
}

// ---------------------------------------------------------------------------
// k2: reduce nch partials -> M unpacked (mirrored) + C.  grid 160 x 128.
// ---------------------------------------------------------------------------
__global__ __launch_bounds__(128) void k2_reduce(
    const float* __restrict__ part, float* __restrict__ Mb,
    float* __restrict__ Cb, int nch) {
  int bid = blockIdx.x;
  int item = bid & 7, chunk = bid >> 3;
  if (TID >= 120) return;
  int q4 = chunk * 120 + TID;             // < 2400
  int off = q4 * 4;
  const float* p = part + (size_t)item * nch * 9600 + off;
  f4 s = f4zero();
  #pragma unroll 8
  for (int c = 0; c < nch; ++c) s = add4(s, ld4(p + (size_t)c * 9600));
  if (off < 4992) {
    int tile = off >> 6, w = (off & 63) >> 2;
    int r = w >> 1, cq = (w & 1) * 4;
    int ti, tj; trimap(tile, ti, tj);
    int i = ti*8 + r, j = tj*8 + cq;
    float* Mi = Mb + (size_t)item * 9216;
    st4(&Mi[i*96 + j], s);
    Mi[(j+0)*96 + i] = s.x; Mi[(j+1)*96 + i] = s.y;
    Mi[(j+2)*96 + i] = s.z; Mi[(j+3)*96 + i] = s.w;
  } else {
    st4(&Cb[(size_t)item * 4608 + (off - 4992)], s);
  }
}

// ---------------------------------------------------------------------------
// kw_phase (r11-proven): LDS-staged wide GEMM phase.  grid nw*8, block 256.
// ---------------------------------------------------------------------------
__global__ __launch_bounds__(256) void kw_phase(
    const float* __restrict__ Ag, const float* __restrict__ Bg,
    const float* __restrict__ Subg, float* __restrict__ Dg, float scale,
    const float* __restrict__ Tin, int ti_istr, int tis, int tsub,
    float* __restrict__ Tout, int to_istr, int tos, int TW) {
  __shared__ __align__(16) float Bs[96][100];   // B-full | A-full
  __shared__ __align__(16) float As[8][100];    // A-slab (square)
  __shared__ __align__(16) float Ts[96][36];    // Tin (thin)
  int bid = blockIdx.x;
  int item = bid & 7, w = bid >> 3, t = TID;
  const float* A = Ag + (size_t)item * 9216;

  if (w < 12) {
    const float* B = Bg + (size_t)item * 9216;
    for (int e = t; e < 2304; e += 256) {            // stage B-full
      int r = e / 24, cq = (e % 24) * 4;
      st4(&Bs[r][cq], ld4(&B[r*96 + cq]));
    }
    if (t < 192) {                                   // stage A-slab
      int r = t / 24, cq = (t % 24) * 4;
      st4(&As[r][cq], ld4(&A[(size_t)(w*8 + r)*96 + cq]));
    }
    __syncthreads();
    if (t < 192) {
      int rl = t / 24, jb = (t % 24) * 4;
      f4 acc = f4zero();
      #pragma unroll 8
      for (int k = 0; k < 96; ++k) fma4(acc, As[rl][k], ld4(&Bs[k][jb]));
      int r = w*8 + rl;
      if (Subg) acc = sub4(ld4(&Subg[(size_t)item*9216 + r*96 + jb]), acc);
      else      acc = scl4(acc, scale);
      st4(&Dg[(size_t)item*9216 + r*96 + jb], acc);
    }
  } else {
    for (int e = t; e < 2304; e += 256) {            // stage A-full
      int r = e / 24, cq = (e % 24) * 4;
      st4(&Bs[r][cq], ld4(&A[r*96 + cq]));
    }
    int nq = TW >> 2;
    const float* Ti = Tin + (size_t)item * ti_istr;
    for (int e = t; e < 96*nq; e += 256) {           // stage Tin
      int r = e / nq, cq = (e % nq) * 4;
      st4(&Ts[r][cq], ld4(&Ti[(size_t)r * tis + cq]));
    }
    __syncthreads();
    int nact = (TW == 32) ? 192 : 96;
    if (t < nact) {
      int r  = (TW == 32) ? (t >> 1) : t;
      int c0 = (TW == 32) ? (t & 1) * 16 : 0;
      f4 acc[4] = {f4zero(), f4zero(), f4zero(), f4zero()};
      #pragma unroll 4
      for (int k = 0; k < 96; ++k) {
        float a = Bs[r][k];
        const float* tr = &Ts[k][c0];
        fma4(acc[0], a, ld4(tr));   fma4(acc[1], a, ld4(tr+4));
        fma4(acc[2], a, ld4(tr+8)); fma4(acc[3], a, ld4(tr+12));
      }
      if (tsub) {
        #pragma unroll
        for (int u = 0; u < 4; ++u) acc[u] = sub4(ld4(&Ts[r][c0 + u*4]), acc[u]);
      }
      float* To = Tout + (size_t)item * to_istr;
      #pragma unroll
      for (int u = 0; u < 4; ++u) st4(&To[(size_t)r * tos + c0 + u*4], acc[u]);
    }
  }
}

// ---------------------------------------------------------------------------
// Wave-register Gauss-Jordan (stride-68 aug), verified r7-r14.
// ---------------------------------------------------------------------------
template<int R>
__device__ void gj_wave(float* aug, int lane) {
  float col[R];
  if (lane < R) {
    #pragma unroll
    for (int i = 0; i < R; ++i) col[i] = aug[i*68 + lane];
  } else {
    #pragma unroll
    for (int i = 0; i < R; ++i) col[i] = (i == lane - R) ? 1.f : 0.f;
  }
  #pragma unroll
  for (int c = 0; c < R; ++c) {
    float pc = __shfl(col[c], c);
    float rp = 1.f / pc;
    bool isc = (lane == c);
    #pragma unroll
    for (int i = 0; i < R; ++i) {
      if (i == c) continue;
      float fi = __shfl(col[i], c) * rp;
      float v = fmaf(-fi, col[c], col[i]);
      col[i] = isc ? 0.f : v;
    }
  }
  #pragma unroll
  for (int i = 0; i < R; ++i) {
    float d = __shfl(col[i], i);
    col[i] = col[i] / d;
  }
  if (lane >= R) {
    #pragma unroll
    for (int i = 0; i < R; ++i) aug[i*68 + lane] = col[i];
  }
}

// ---------------------------------------------------------------------------
// kWproj3<TW,MODE> v2: S staged K-MAJOR (St[k][r]); 3 thin passes as 4x4
// register tiles (2 b128/k for 4 f4 outputs); Gram 4x4-tiled; wave-GJ;
// QK slab; W slab.  grid 96 (item = bid&7, w = bid>>3), block 256.
// MODE 1: W -> W1g.  MODE 2: Tg = W1g + W.
// smem: St[96][100]@0, Ta[96][36]@9600, Tb[96][36]@13056, aug[32][68]@16512,
// QKs[8][32]@18688 -> 18944 floats (75.8 KB).
// ---------------------------------------------------------------------------
template<int TW, int MODE>
__global__ __launch_bounds__(256) void kWproj3(
    const float* __restrict__ Sg, const float* __restrict__ Yg,
    float* __restrict__ W1g, float* __restrict__ Tgg) {
  __shared__ __align__(16) float smem[18944];
  float* St  = smem;            // [96][100]  St[k][r] = S[r][k]
  float* Ta  = smem + 9600;     // [96][36]
  float* Tb  = smem + 13056;    // [96][36]
  float* aug = smem + 16512;    // [32][68]
  float* QKs = smem + 18688;    // [8][32]

  int bid = blockIdx.x;
  int item = bid & 7, w = bid >> 3, t = TID;
  const float* S = Sg + (size_t)item * 9216;
  const float* Y = Yg + (size_t)item * 3072;
  float* W1 = W1g + (size_t)item * 9216;
  float* Tg = Tgg + (size_t)item * 9216;
  const int nq = TW >> 2;

  // s0: stage S transposed (k-major) + Y
  for (int e = t; e < 2304; e += 256) {
    int r = e / 24, cq = (e % 24) * 4;
    f4 v = ld4(&S[r*96 + cq]);
    St[(cq+0)*100 + r] = v.x; St[(cq+1)*100 + r] = v.y;
    St[(cq+2)*100 + r] = v.z; St[(cq+3)*100 + r] = v.w;
  }
  for (int e = t; e < 96*nq; e += 256) {
    int r = e / nq, cq = (e % nq) * 4;
    st4(&Ta[r*36 + cq], ld4(&Y[r*32 + cq]));
  }
  __syncthreads();

  // s1-s3: Tb = S*Ta; Ta = S*Tb; Tb = S*Ta   (P, P2, Q)  — 4x4 reg tiles
  #pragma unroll
  for (int pass = 0; pass < 3; ++pass) {
    const float* src = (pass & 1) ? Tb : Ta;
    float* dst       = (pass & 1) ? Ta : Tb;
    int ntask = 24 * nq;               // 192 (TW=32) or 96 (TW=16)
    if (t < ntask) {
      int rb = (t / nq) * 4, c4 = (t % nq) * 4;
      f4 acc[4] = {f4zero(), f4zero(), f4zero(), f4zero()};
      #pragma unroll 4
      for (int k = 0; k < 96; ++k) {
        f4 s = ld4(&St[k*100 + rb]);
        f4 v = ld4(&src[k*36 + c4]);
        fma4(acc[0], s.x, v); fma4(acc[1], s.y, v);
        fma4(acc[2], s.z, v); fma4(acc[3], s.w, v);
      }
      #pragma unroll
      for (int j = 0; j < 4; ++j) st4(&dst[(rb + j)*36 + c4], acc[j]);
    }
    __syncthreads();
  }
  // Q now in Tb.

  // s4: Gram = Q^T Q -> aug[:,0:TW]  (4x4 reg tiles)
  {
    int na = TW >> 2;
    if (t < na*na) {
      int ab = (t / na) * 4, b4 = (t % na) * 4;
      f4 acc[4] = {f4zero(), f4zero(), f4zero(), f4zero()};
      #pragma unroll 4
      for (int k = 0; k < 96; ++k) {
        f4 qa = ld4(&Tb[k*36 + ab]);
        f4 qb = ld4(&Tb[k*36 + b4]);
        fma4(acc[0], qa.x, qb); fma4(acc[1], qa.y, qb);
        fma4(acc[2], qa.z, qb); fma4(acc[3], qa.w, qb);
      }
      #pragma unroll
      for (int j = 0; j < 4; ++j) st4(&aug[(ab + j)*68 + b4], acc[j]);
    }
  }
  __syncthreads();

  // s5: wave-GJ -> K in aug[:,TW:2TW]; K^T -> aug[:,0:TW]
  if (t < 2*TW) gj_wave<TW>(aug, t);
  __syncthreads();
  for (int e = t; e < TW*TW; e += 256) {
    int m = e / TW, c = e % TW;
    aug[c*68 + m] = aug[m*68 + TW + c];
  }
  __syncthreads();

  // s6: QK slab (rows w*8..w*8+8)
  for (int e = t; e < 8*TW; e += 256) {
    int rr = e / TW, c = e % TW;
    float acc = 0.f;
    #pragma unroll
    for (int m4 = 0; m4 < TW; m4 += 4)
      acc = dot4(ld4(&Tb[(w*8 + rr)*36 + m4]), ld4(&aug[c*68 + m4]), acc);
    QKs[rr*32 + c] = acc;
  }
  __syncthreads();

  // s7: W slab = QK * Q^T
  if (t < 192) {
    int rr = t / 24, jb = (t % 24) * 4;
    int r = w*8 + rr;
    f4 acc = f4zero();
    #pragma unroll
    for (int c4 = 0; c4 < TW; c4 += 4) {
      f4 qk = ld4(&QKs[rr*32 + c4]);
      acc.x = dot4(qk, ld4(&Tb[(jb+0)*36 + c4]), acc.x);
      acc.y = dot4(qk, ld4(&Tb[(jb+1)*36 + c4]), acc.y);
      acc.z = dot4(qk, ld4(&Tb[(jb+2)*36 + c4]), acc.z);
      acc.w = dot4(qk, ld4(&Tb[(jb+3)*36 + c4]), acc.w);
    }
    if (MODE == 1) st4(&W1[r*96 + jb], acc);
    else           st4(&Tg[r*96 + jb], add4(acc, ld4(&W1[r*96 + jb])));
  }
}

// ---------------------------------------------------------------------------
// k4: out = T @ X.  grid 576 (item = bid&7), block 256.
// ---------------------------------------------------------------------------
__global__ __launch_bounds__(256) void k4_out(
    const float* __restrict__ x, const float* __restrict__ Tgg,
    float* __restrict__ out) {
  __shared__ __align__(16) float Tt[96][100];
  int bid = blockIdx.x;
  int item = bid & 7, jb = bid >> 3;
  const float* Tg = Tgg + (size_t)item * 9216;
  for (int e = TID * 4; e < 9216; e += 1024) {
    f4 v = ld4(&Tg[e]);
    int i = e / 96, k = e % 96;
    Tt[k][i] = v.x; Tt[k+1][i] = v.y; Tt[k+2][i] = v.z; Tt[k+3][i] = v.w;
  }
  __syncthreads();

  int jq = (TID % 32) * 4, ig = TID / 32;
  int i0 = ig * 12;
  int col = jb * 128 + jq;
  const float* X = x + (size_t)item * 96 * 9216;
  f4 acc[12];
  #pragma unroll
  for (int a = 0; a < 12; ++a) acc[a] = f4zero();

  for (int k = 0; k < 96; ++k) {
    f4 xv = ld4(&X[(size_t)k * 9216 + col]);
    f4 t0 = ld4(&Tt[k][i0]), t1 = ld4(&Tt[k][i0+4]), t2 = ld4(&Tt[k][i0+8]);
    fma4(acc[0], t0.x, xv); fma4(acc[1], t0.y, xv); fma4(acc[2], t0.z, xv); fma4(acc[3], t0.w, xv);
    fma4(acc[4], t1.x, xv); fma4(acc[5], t1.y, xv); fma4(acc[6], t1.z, xv); fma4(acc[7], t1.w, xv);
    fma4(acc[8], t2.x, xv); fma4(acc[9], t2.y, xv); fma4(acc[10], t2.z, xv); fma4(acc[11], t2.w, xv);
  }
  float* O = out + (size_t)item * 96 * 9216;
  #pragma unroll
  for (int a = 0; a < 12; ++a) st4(&O[(size_t)(i0 + a) * 9216 + col], acc[a]);
}

// ---------------------------------------------------------------------------
extern "C" void kernel_launch(void* const* d_in, const int* in_sizes, int n_in,
                              void* d_out, int out_size, void* d_ws, size_t ws_size,
                              hipStream_t stream) {
  (void)in_sizes; (void)n_in; (void)out_size;
  const float* x   = (const float*)d_in[0];
  const float* b01 = (const float*)d_in[2];
  const float* b02 = (const float*)d_in[4];
  float* out = (float*)d_out;
  float* ws  = (float*)d_ws;

  const size_t EXTRA = 73728ull*5 + 36864 + 24576 + 12288;
  int nch = (ws_size >= ((size_t)64*8*9600 + EXTRA) * sizeof(float)) ? 64 : 32;
  int nsc = 9216 / nch / 48;

  float* Mb  = ws + (size_t)nch * 8 * 9600;
  float* Cb  = Mb  + 73728;
  float* Sb  = Cb  + 36864;    // S1 / TMP / S1'
  float* S2b = Sb  + 73728;
  float* W1b = S2b + 73728;
  float* Tgb = W1b + 73728;
  float* Yb  = Tgb + 73728;
  float* CPb = Yb  + 24576;

  k1_partials<<<dim3(nch*8), 512, 0, stream>>>(x, b01, b02, ws, nch, nsc);
  k2_reduce<<<dim3(160), 128, 0, stream>>>(ws, Mb, Cb, nch);

  // partition 1
  kw_phase<<<dim3(96),256,0,stream>>>(Mb, Mb, nullptr, Sb, SC27,
      nullptr,0,0,0, nullptr,0,0, 0);                                   // S1 = M^2*s
  kw_phase<<<dim3(104),256,0,stream>>>(Sb, Sb, nullptr, S2b, 1.f,
      Cb,4608,48,0, Yb,3072,32, 32);                                    // S2 ; Y = S1*C1
  kWproj3<32,1><<<dim3(96),256,0,stream>>>(S2b, Yb, W1b, Tgb);          // W1 = proj(S2^3 Y)

  // M2 construction
  kw_phase<<<dim3(104),256,0,stream>>>(W1b, Mb, Mb, Sb, 1.f,
      Cb+32,4608,48,1, CPb,1536,16, 16);                                // TMP = M - W1*M ; C2'
  kw_phase<<<dim3(96),256,0,stream>>>(Sb, W1b, Sb, Mb, 1.f,
      nullptr,0,0,0, nullptr,0,0, 0);                                   // M2 = TMP - TMP*W1

  // partition 2
  kw_phase<<<dim3(96),256,0,stream>>>(Mb, Mb, nullptr, Sb, SC27,
      nullptr,0,0,0, nullptr,0,0, 0);                                   // S1' = M2^2*s
  kw_phase<<<dim3(104),256,0,stream>>>(Sb, Sb, nullptr, S2b, 1.f,
      CPb,1536,16,0, Yb,3072,32, 16);                                   // S2' ; Y' = S1'*C2'
  kWproj3<16,2><<<dim3(96),256,0,stream>>>(S2b, Yb, W1b, Tgb);          // Tg = W1 + proj(S2'^3 Y')

  k4_out<<<dim3(576), 256, 0, stream>>>(x, Tgb, out);
}